// Round 1
// baseline (1778.622 us; speedup 1.0000x reference)
//
#include <hip/hip_runtime.h>
#include <math.h>

// CrossFeatureTransformer fused kernel — one block per (b,h), fp32 vector baseline.
// B=16,H=64 -> 1024 blocks of 256 threads; thread = output channel c.

#define NN   128
#define CC   256
#define HIDN 1024
#define C8   32
#define EPSL 1e-6f
#define NCHUNK  32
#define NCHUNKS (NN / NCHUNK)
#define ATS 260   // padded stride for attn_in LDS tile (4-aligned, bank-staggered)
#define PHS 36    // padded stride for 32-wide hidden tiles

__device__ __forceinline__ float block_sum_256(float v, float* red) {
    #pragma unroll
    for (int off = 32; off > 0; off >>= 1)
        v += __shfl_down(v, off, 64);
    const int wid = threadIdx.x >> 6;
    if ((threadIdx.x & 63) == 0) red[wid] = v;
    __syncthreads();
    float s = red[0] + red[1] + red[2] + red[3];
    __syncthreads();
    return s;
}

__global__ __launch_bounds__(256, 2)
void cft_fused(const float* __restrict__ qin, const float* __restrict__ kin,
               const float* __restrict__ rel, const int* __restrict__ vis,
               const float* __restrict__ ln1g, const float* __restrict__ ln1b,
               const float* __restrict__ ln2g, const float* __restrict__ ln2b,
               const float* __restrict__ Wq,  const float* __restrict__ Wk,
               const float* __restrict__ Wv,
               const float* __restrict__ pw1, const float* __restrict__ pb1,
               const float* __restrict__ pw2, const float* __restrict__ pb2,
               const float* __restrict__ sw1, const float* __restrict__ sb1,
               const float* __restrict__ sw2, const float* __restrict__ sb2,
               const float* __restrict__ Wo,  const float* __restrict__ bo,
               const float* __restrict__ fw1, const float* __restrict__ fb1,
               const float* __restrict__ fw2, const float* __restrict__ fb2,
               float* __restrict__ out)
{
    __shared__ float at[NCHUNK * ATS];   // attn_in staging  (33.3 KB)
    __shared__ float ph[NCHUNK * PHS];   // pos-MLP hidden   (4.6 KB)
    __shared__ float h1s[NCHUNK * PHS];  // score-MLP hidden (4.6 KB)
    __shared__ float xlnL[CC];           // LN row / agg / LN2 row (reused)
    __shared__ float ffh[HIDN];          // FF hidden
    __shared__ float red[4];

    const int bh = blockIdx.x;
    const int c  = threadIdx.x;
    const float* kbase = kin + (size_t)bh * NN * CC;

    // ---- phase 0: LN1(query) + q = ln @ Wq ----
    const float xq = qin[bh * CC + c];
    const float mean = block_sum_256(xq, red) * (1.0f / CC);
    const float dd = xq - mean;
    const float var = block_sum_256(dd * dd, red) * (1.0f / CC);
    const float xn = dd * rsqrtf(var + EPSL) * ln1g[c] + ln1b[c];
    xlnL[c] = xn;
    __syncthreads();

    float qc = 0.0f;
    for (int k4 = 0; k4 < CC / 4; ++k4) {
        float4 xv = *(const float4*)&xlnL[k4 * 4];
        const float* w = Wq + (size_t)(k4 * 4) * CC + c;
        qc = fmaf(xv.x, w[0],      qc);
        qc = fmaf(xv.y, w[CC],     qc);
        qc = fmaf(xv.z, w[2 * CC], qc);
        qc = fmaf(xv.w, w[3 * CC], qc);
    }

    // hoisted pos_w2 column (constant across chunks)
    float wp[C8];
    #pragma unroll
    for (int j = 0; j < C8; ++j) wp[j] = pw2[j * CC + c];
    const float pb2c = pb2[c];
    const float sb2c = sb2[c];

    // per-channel online softmax state
    float m = -INFINITY, l = 0.0f, agg = 0.0f;

    for (int cc = 0; cc < NCHUNKS; ++cc) {
        const int n0 = cc * NCHUNK;
        __syncthreads();  // protect ph/h1s reuse against previous-iter readers

        // (a) pos-MLP hidden: ph[n][j] = relu(rel @ pos_w1 + pos_b1)
        {
            const int n  = c & 31;
            const int j0 = c >> 5;  // 0..7, covers j0+8q
            const float* rp = rel + ((size_t)bh * NN + n0 + n) * 4;
            const float r0 = rp[0], r1 = rp[1], r2 = rp[2], r3 = rp[3];
            #pragma unroll
            for (int qq = 0; qq < 4; ++qq) {
                const int j = j0 + 8 * qq;
                float v0 = pb1[j];
                v0 = fmaf(r0, pw1[j],          v0);
                v0 = fmaf(r1, pw1[C8 + j],     v0);
                v0 = fmaf(r2, pw1[2 * C8 + j], v0);
                v0 = fmaf(r3, pw1[3 * C8 + j], v0);
                ph[n * PHS + j] = fmaxf(v0, 0.0f);
            }
        }
        __syncthreads();

        // (b) k/v projections over the chunk + pos + attn_in
        float ak[NCHUNK], av[NCHUNK];
        #pragma unroll
        for (int n = 0; n < NCHUNK; ++n) { ak[n] = 0.0f; av[n] = 0.0f; }

        for (int k4 = 0; k4 < CC / 4; ++k4) {
            const int k = k4 * 4;
            const float* wkp = Wk + (size_t)k * CC + c;
            const float* wvp = Wv + (size_t)k * CC + c;
            const float wk0 = wkp[0], wk1 = wkp[CC], wk2 = wkp[2 * CC], wk3 = wkp[3 * CC];
            const float wv0 = wvp[0], wv1 = wvp[CC], wv2 = wvp[2 * CC], wv3 = wvp[3 * CC];
            #pragma unroll
            for (int n = 0; n < NCHUNK; ++n) {
                // wave-uniform address -> expect s_load_dwordx4
                float4 kv = *(const float4*)(kbase + (size_t)(n0 + n) * CC + k);
                ak[n] = fmaf(kv.x, wk0, ak[n]);
                ak[n] = fmaf(kv.y, wk1, ak[n]);
                ak[n] = fmaf(kv.z, wk2, ak[n]);
                ak[n] = fmaf(kv.w, wk3, ak[n]);
                av[n] = fmaf(kv.x, wv0, av[n]);
                av[n] = fmaf(kv.y, wv1, av[n]);
                av[n] = fmaf(kv.z, wv2, av[n]);
                av[n] = fmaf(kv.w, wv3, av[n]);
            }
        }

        #pragma unroll
        for (int n = 0; n < NCHUNK; ++n) {
            float p = pb2c;
            #pragma unroll
            for (int j4 = 0; j4 < C8 / 4; ++j4) {
                float4 pv = *(const float4*)&ph[n * PHS + j4 * 4];
                p = fmaf(pv.x, wp[j4 * 4 + 0], p);
                p = fmaf(pv.y, wp[j4 * 4 + 1], p);
                p = fmaf(pv.z, wp[j4 * 4 + 2], p);
                p = fmaf(pv.w, wp[j4 * 4 + 3], p);
            }
            at[n * ATS + c] = ak[n] - qc + p;  // attn_in
            av[n] += p;                         // v + pos
        }
        __syncthreads();

        // (c) h1 = relu(attn_in @ sc_w1 + sc_b1)  — thread covers (n, 4 j's)
        {
            const int n  = c & 31;
            const int j0 = c >> 5;
            float hv0 = sb1[j0], hv1 = sb1[j0 + 8], hv2 = sb1[j0 + 16], hv3 = sb1[j0 + 24];
            for (int c4 = 0; c4 < CC / 4; ++c4) {
                float4 a4 = *(const float4*)&at[n * ATS + c4 * 4];
                float aa[4] = {a4.x, a4.y, a4.z, a4.w};
                #pragma unroll
                for (int i = 0; i < 4; ++i) {
                    const float* w0 = sw1 + (size_t)(c4 * 4 + i) * C8 + j0;
                    hv0 = fmaf(aa[i], w0[0],  hv0);
                    hv1 = fmaf(aa[i], w0[8],  hv1);
                    hv2 = fmaf(aa[i], w0[16], hv2);
                    hv3 = fmaf(aa[i], w0[24], hv3);
                }
            }
            h1s[n * PHS + j0]      = fmaxf(hv0, 0.0f);
            h1s[n * PHS + j0 + 8]  = fmaxf(hv1, 0.0f);
            h1s[n * PHS + j0 + 16] = fmaxf(hv2, 0.0f);
            h1s[n * PHS + j0 + 24] = fmaxf(hv3, 0.0f);
        }
        __syncthreads();

        // (d) scores + mask + per-channel online softmax update
        {
            float wb[C8];
            #pragma unroll
            for (int j = 0; j < C8; ++j) wb[j] = sw2[j * CC + c];
            #pragma unroll 4
            for (int n = 0; n < NCHUNK; ++n) {
                float s = sb2c;
                #pragma unroll
                for (int j4 = 0; j4 < C8 / 4; ++j4) {
                    float4 hh = *(const float4*)&h1s[n * PHS + j4 * 4];
                    s = fmaf(hh.x, wb[j4 * 4 + 0], s);
                    s = fmaf(hh.y, wb[j4 * 4 + 1], s);
                    s = fmaf(hh.z, wb[j4 * 4 + 2], s);
                    s = fmaf(hh.w, wb[j4 * 4 + 3], s);
                }
                if (vis[(size_t)bh * NN + n0 + n] == 0) s = -1e9f;
                const float mn = fmaxf(m, s);
                const float al = __expf(m - mn);   // exp(-inf)=0 on first iter
                const float w  = __expf(s - mn);
                l = l * al + w;
                agg = fmaf(w, av[n], agg * al);
                m = mn;
            }
        }
    }

    // ---- epilogue ----
    const float aggf = agg / l;   // all-masked row => l=128, no div0
    xlnL[c] = aggf;
    __syncthreads();

    float ao = bo[c];
    for (int k4 = 0; k4 < CC / 4; ++k4) {
        float4 a4 = *(const float4*)&xlnL[k4 * 4];
        const float* w = Wo + (size_t)(k4 * 4) * CC + c;
        ao = fmaf(a4.x, w[0],      ao);
        ao = fmaf(a4.y, w[CC],     ao);
        ao = fmaf(a4.z, w[2 * CC], ao);
        ao = fmaf(a4.w, w[3 * CC], ao);
    }
    const float xres = ao + xq;  // residual with ORIGINAL query

    // LN2 (block_sum barriers also fence the xlnL reads above)
    const float mean2 = block_sum_256(xres, red) * (1.0f / CC);
    const float d2 = xres - mean2;
    const float var2 = block_sum_256(d2 * d2, red) * (1.0f / CC);
    const float yn = d2 * rsqrtf(var2 + EPSL) * ln2g[c] + ln2b[c];
    xlnL[c] = yn;
    __syncthreads();

    // FF hidden: 4 units per thread
    #pragma unroll
    for (int r = 0; r < 4; ++r) {
        const int hh = c + 256 * r;
        float hv = fb1[hh];
        for (int c4 = 0; c4 < CC / 4; ++c4) {
            float4 xv = *(const float4*)&xlnL[c4 * 4];
            const float* w = fw1 + (size_t)(c4 * 4) * HIDN + hh;
            hv = fmaf(xv.x, w[0],        hv);
            hv = fmaf(xv.y, w[HIDN],     hv);
            hv = fmaf(xv.z, w[2 * HIDN], hv);
            hv = fmaf(xv.w, w[3 * HIDN], hv);
        }
        ffh[hh] = fmaxf(hv, 0.0f);
    }
    __syncthreads();

    float o = xres + fb2[c];
    for (int h4 = 0; h4 < HIDN / 4; ++h4) {
        float4 hv4 = *(const float4*)&ffh[h4 * 4];
        const float* w = fw2 + (size_t)(h4 * 4) * CC + c;
        o = fmaf(hv4.x, w[0],      o);
        o = fmaf(hv4.y, w[CC],     o);
        o = fmaf(hv4.z, w[2 * CC], o);
        o = fmaf(hv4.w, w[3 * CC], o);
    }
    out[bh * CC + c] = o;
}

extern "C" void kernel_launch(void* const* d_in, const int* in_sizes, int n_in,
                              void* d_out, int out_size, void* d_ws, size_t ws_size,
                              hipStream_t stream) {
    const float* qin  = (const float*)d_in[0];
    const float* kin  = (const float*)d_in[1];
    const float* rel  = (const float*)d_in[2];
    const int*   vis  = (const int*)  d_in[3];
    const float* ln1g = (const float*)d_in[4];
    const float* ln1b = (const float*)d_in[5];
    const float* ln2g = (const float*)d_in[6];
    const float* ln2b = (const float*)d_in[7];
    const float* Wq   = (const float*)d_in[8];
    const float* Wk   = (const float*)d_in[9];
    const float* Wv   = (const float*)d_in[10];
    const float* pw1  = (const float*)d_in[11];
    const float* pb1  = (const float*)d_in[12];
    const float* pw2  = (const float*)d_in[13];
    const float* pb2  = (const float*)d_in[14];
    const float* sw1  = (const float*)d_in[15];
    const float* sb1  = (const float*)d_in[16];
    const float* sw2  = (const float*)d_in[17];
    const float* sb2  = (const float*)d_in[18];
    const float* Wo   = (const float*)d_in[19];
    const float* bo   = (const float*)d_in[20];
    const float* fw1  = (const float*)d_in[21];
    const float* fb1  = (const float*)d_in[22];
    const float* fw2  = (const float*)d_in[23];
    const float* fb2  = (const float*)d_in[24];
    float* o = (float*)d_out;

    cft_fused<<<dim3(1024), dim3(256), 0, stream>>>(
        qin, kin, rel, vis, ln1g, ln1b, ln2g, ln2b, Wq, Wk, Wv,
        pw1, pb1, pw2, pb2, sw1, sb1, sw2, sb2, Wo, bo,
        fw1, fb1, fw2, fb2, o);
}

// Round 2
// 620.077 us; speedup vs baseline: 2.8684x; 2.8684x over previous
//
#include <hip/hip_runtime.h>
#include <math.h>

#define NN 128
#define CC 256
#define HIDN 1024
#define LDST 296          // buf row stride (bf16 elems): 256 attn + 32 aux + 8 pad
#define EPSL 1e-6f

typedef short s16x8 __attribute__((ext_vector_type(8)));
typedef float f32x4 __attribute__((ext_vector_type(4)));

// ---- workspace layout ----
// bf16 units unless noted. frag blobs: wk [ct16][kt9][64][8], wv same, sw1 [jt2][kt8][64][8], sw2 [ct16][kt1][64][8]
#define WKOFF   0
#define WVOFF   73728
#define SW1OFF  147456
#define SW2OFF  155648
#define NFRAG   163840
#define XRES_BYTE_OFF 327680              // f32 [1024*256]
#define FW1B_OFF 688128                   // bf16 units (byte 1376256)
#define FW2B_OFF 950272
#define WOB_OFF  1212416
#define NPREP   753664                    // 163840 + 262144 + 262144 + 65536

__device__ __forceinline__ unsigned short f2b(float x) {
    unsigned u = __builtin_bit_cast(unsigned, x);
    u += 0x7fffu + ((u >> 16) & 1u);
    return (unsigned short)(u >> 16);
}
__device__ __forceinline__ float b2f(unsigned short s) {
    return __builtin_bit_cast(float, ((unsigned)s) << 16);
}
__device__ __forceinline__ unsigned pack2(float a, float b) {
    return (unsigned)f2b(a) | ((unsigned)f2b(b) << 16);
}

__device__ __forceinline__ float block_sum_256(float v, float* red) {
    #pragma unroll
    for (int off = 32; off > 0; off >>= 1)
        v += __shfl_down(v, off, 64);
    const int wid = threadIdx.x >> 6;
    if ((threadIdx.x & 63) == 0) red[wid] = v;
    __syncthreads();
    float s = red[0] + red[1] + red[2] + red[3];
    __syncthreads();
    return s;
}

// ---------------- prep: build bf16 fragment blobs + bf16 weight copies ----------------
__global__ __launch_bounds__(256)
void prep_frags(const float* __restrict__ Wk, const float* __restrict__ Wv,
                const float* __restrict__ pw2, const float* __restrict__ sw1,
                const float* __restrict__ sw2, const float* __restrict__ fw1,
                const float* __restrict__ fw2, const float* __restrict__ Wo,
                unsigned short* __restrict__ ws16)
{
    int e = blockIdx.x * 256 + threadIdx.x;
    if (e >= NPREP) return;
    if (e < NFRAG) {
        float val;
        if (e < SW1OFF) {  // wk or wv blob (with pw2 as kt==8)
            const float* W = (e < WVOFF) ? Wk : Wv;
            int local = (e < WVOFF) ? e : e - WVOFF;
            int ct = local / 4608;            // 9*512
            int rem = local % 4608;
            int kt = rem / 512;
            int l = (rem % 512) / 8;
            int j = rem % 8;
            int k = kt * 32 + (l >> 4) * 8 + j;
            int col = ct * 16 + (l & 15);
            val = (kt < 8) ? W[k * CC + col] : pw2[(k - 256) * CC + col];
        } else if (e < SW2OFF) {
            int local = e - SW1OFF;
            int jt = local / 4096;
            int rem = local % 4096;
            int kt = rem / 512;
            int l = (rem % 512) / 8;
            int j = rem % 8;
            int k = kt * 32 + (l >> 4) * 8 + j;
            val = sw1[k * 32 + jt * 16 + (l & 15)];
        } else {
            int local = e - SW2OFF;
            int ct = local / 512;
            int l = (local % 512) / 8;
            int j = local % 8;
            int k = (l >> 4) * 8 + j;
            val = sw2[k * CC + ct * 16 + (l & 15)];
        }
        ws16[e] = f2b(val);
    } else if (e < NFRAG + 262144) {
        int i = e - NFRAG;
        ws16[FW1B_OFF + i] = f2b(fw1[i]);
    } else if (e < NFRAG + 524288) {
        int i = e - NFRAG - 262144;
        ws16[FW2B_OFF + i] = f2b(fw2[i]);
    } else {
        int i = e - NFRAG - 524288;
        ws16[WOB_OFF + i] = f2b(Wo[i]);
    }
}

// ---------------- k1: attention (one block per (b,h)) ----------------
__global__ __launch_bounds__(256, 2)
void cft_attn(const float* __restrict__ qin, const float* __restrict__ kin,
              const float* __restrict__ rel, const int* __restrict__ vis,
              const float* __restrict__ ln1g, const float* __restrict__ ln1b,
              const float* __restrict__ Wq,
              const float* __restrict__ pw1, const float* __restrict__ pb1,
              const float* __restrict__ pb2,
              const float* __restrict__ sb1, const float* __restrict__ sb2,
              const float* __restrict__ bo,
              const unsigned short* __restrict__ ws16,
              float* __restrict__ xres)
{
    __shared__ __align__(16) unsigned short buf[NN * LDST];  // 75776 B
    __shared__ __align__(16) float poolA[CC];                // xln -> (pb2 - q)
    __shared__ __align__(16) float poolC[1024];              // softmax tables -> agg
    __shared__ unsigned char visb[NN];
    __shared__ float red[8];

    const int bh = blockIdx.x;
    const int t = threadIdx.x;
    const int lane = t & 63;
    const int wvid = t >> 6;
    const int quad = lane >> 4;
    const int l16 = lane & 15;

    // ---- setup: stage keys -> bf16 LDS, pos hidden, vis, LN1+q ----
    const float4* kb4 = (const float4*)(kin + (size_t)bh * NN * CC);
    #pragma unroll
    for (int i = 0; i < 32; ++i) {
        int flat = i * 256 + t;
        int row = flat >> 6;
        int cu = flat & 63;
        float4 kv = kb4[flat];
        uint2 pk;
        pk.x = pack2(kv.x, kv.y);
        pk.y = pack2(kv.z, kv.w);
        *(uint2*)&buf[row * LDST + cu * 4] = pk;
    }
    if (t < NN) visb[t] = (unsigned char)(vis[(size_t)bh * NN + t] != 0);
    {   // ph = relu(rel @ pw1 + pb1) -> buf cols 256..287
        int r = t >> 1, jh = (t & 1) * 16;
        float4 rp = *(const float4*)(rel + ((size_t)bh * NN + r) * 4);
        #pragma unroll
        for (int jj = 0; jj < 16; ++jj) {
            int j = jh + jj;
            float v0 = pb1[j];
            v0 = fmaf(rp.x, pw1[j], v0);
            v0 = fmaf(rp.y, pw1[32 + j], v0);
            v0 = fmaf(rp.z, pw1[64 + j], v0);
            v0 = fmaf(rp.w, pw1[96 + j], v0);
            buf[r * LDST + 256 + j] = f2b(fmaxf(v0, 0.0f));
        }
    }
    const float xq = qin[(size_t)bh * CC + t];
    float mean = block_sum_256(xq, red) * (1.0f / CC);
    float dd = xq - mean;
    float var = block_sum_256(dd * dd, red) * (1.0f / CC);
    poolA[t] = dd * rsqrtf(var + EPSL) * ln1g[t] + ln1b[t];
    __syncthreads();
    float qv = 0.0f;
    for (int k4 = 0; k4 < CC / 4; ++k4) {
        float4 xv = *(const float4*)&poolA[k4 * 4];
        const float* w = Wq + (size_t)(k4 * 4) * CC + t;
        qv = fmaf(xv.x, w[0], qv);
        qv = fmaf(xv.y, w[CC], qv);
        qv = fmaf(xv.z, w[2 * CC], qv);
        qv = fmaf(xv.w, w[3 * CC], qv);
    }
    __syncthreads();
    poolA[t] = pb2[t] - qv;   // qm
    __syncthreads();

    // ---- GEMM1: attn_pre = Kin@Wk + ph@pw2 ; vpp = Kin@Wv + ph@pw2 + pb2 ----
    const int rb = wvid * 32;
    const int aoff0 = (rb + l16) * LDST;
    const int aoff1 = (rb + 16 + l16) * LDST;
    unsigned vppq[2][16][2];
    unsigned attq[2][16][2];
    const unsigned short* wsk = ws16 + WKOFF;
    const unsigned short* wsv = ws16 + WVOFF;

    #pragma unroll
    for (int ch = 0; ch < 2; ++ch) {
        f32x4 acc[2][8];
        // Vp + pos
        #pragma unroll
        for (int mt = 0; mt < 2; ++mt)
            #pragma unroll
            for (int c8 = 0; c8 < 8; ++c8) acc[mt][c8] = (f32x4){0.f, 0.f, 0.f, 0.f};
        for (int kt = 0; kt < 9; ++kt) {
            s16x8 A0 = *(const s16x8*)&buf[aoff0 + kt * 32 + quad * 8];
            s16x8 A1 = *(const s16x8*)&buf[aoff1 + kt * 32 + quad * 8];
            const unsigned short* bp = wsv + ((size_t)(ch * 8) * 9 + kt) * 512 + lane * 8;
            #pragma unroll
            for (int c8 = 0; c8 < 8; ++c8) {
                s16x8 B = *(const s16x8*)(bp + (size_t)c8 * 9 * 512);
                acc[0][c8] = __builtin_amdgcn_mfma_f32_16x16x32_bf16(A0, B, acc[0][c8], 0, 0, 0);
                acc[1][c8] = __builtin_amdgcn_mfma_f32_16x16x32_bf16(A1, B, acc[1][c8], 0, 0, 0);
            }
        }
        #pragma unroll
        for (int c8 = 0; c8 < 8; ++c8) {
            int ct = ch * 8 + c8;
            float pb = pb2[ct * 16 + l16];
            #pragma unroll
            for (int mt = 0; mt < 2; ++mt) {
                vppq[mt][ct][0] = pack2(acc[mt][c8][0] + pb, acc[mt][c8][1] + pb);
                vppq[mt][ct][1] = pack2(acc[mt][c8][2] + pb, acc[mt][c8][3] + pb);
            }
        }
        // attn pre
        #pragma unroll
        for (int mt = 0; mt < 2; ++mt)
            #pragma unroll
            for (int c8 = 0; c8 < 8; ++c8) acc[mt][c8] = (f32x4){0.f, 0.f, 0.f, 0.f};
        for (int kt = 0; kt < 9; ++kt) {
            s16x8 A0 = *(const s16x8*)&buf[aoff0 + kt * 32 + quad * 8];
            s16x8 A1 = *(const s16x8*)&buf[aoff1 + kt * 32 + quad * 8];
            const unsigned short* bp = wsk + ((size_t)(ch * 8) * 9 + kt) * 512 + lane * 8;
            #pragma unroll
            for (int c8 = 0; c8 < 8; ++c8) {
                s16x8 B = *(const s16x8*)(bp + (size_t)c8 * 9 * 512);
                acc[0][c8] = __builtin_amdgcn_mfma_f32_16x16x32_bf16(A0, B, acc[0][c8], 0, 0, 0);
                acc[1][c8] = __builtin_amdgcn_mfma_f32_16x16x32_bf16(A1, B, acc[1][c8], 0, 0, 0);
            }
        }
        #pragma unroll
        for (int c8 = 0; c8 < 8; ++c8) {
            int ct = ch * 8 + c8;
            float qm = poolA[ct * 16 + l16];
            #pragma unroll
            for (int mt = 0; mt < 2; ++mt) {
                attq[mt][ct][0] = pack2(acc[mt][c8][0] + qm, acc[mt][c8][1] + qm);
                attq[mt][ct][1] = pack2(acc[mt][c8][2] + qm, acc[mt][c8][3] + qm);
            }
        }
    }
    // write attn_in (bf16) in place over key rows (own slab)
    #pragma unroll
    for (int mt = 0; mt < 2; ++mt)
        #pragma unroll
        for (int ct = 0; ct < 16; ++ct) {
            int col = ct * 16 + l16;
            int rw = rb + mt * 16 + quad * 4;
            unsigned p0 = attq[mt][ct][0], p1 = attq[mt][ct][1];
            buf[(rw + 0) * LDST + col] = (unsigned short)p0;
            buf[(rw + 1) * LDST + col] = (unsigned short)(p0 >> 16);
            buf[(rw + 2) * LDST + col] = (unsigned short)p1;
            buf[(rw + 3) * LDST + col] = (unsigned short)(p1 >> 16);
        }
    __syncthreads();

    // ---- GEMM2: h1 = relu(attn@sw1 + sb1) -> buf cols 256..287 ----
    {
        f32x4 h[2][2];
        #pragma unroll
        for (int mt = 0; mt < 2; ++mt)
            #pragma unroll
            for (int jt = 0; jt < 2; ++jt) h[mt][jt] = (f32x4){0.f, 0.f, 0.f, 0.f};
        const unsigned short* ws1 = ws16 + SW1OFF;
        for (int kt = 0; kt < 8; ++kt) {
            s16x8 A0 = *(const s16x8*)&buf[aoff0 + kt * 32 + quad * 8];
            s16x8 A1 = *(const s16x8*)&buf[aoff1 + kt * 32 + quad * 8];
            #pragma unroll
            for (int jt = 0; jt < 2; ++jt) {
                s16x8 B = *(const s16x8*)(ws1 + ((size_t)(jt * 8 + kt) * 64 + lane) * 8);
                h[0][jt] = __builtin_amdgcn_mfma_f32_16x16x32_bf16(A0, B, h[0][jt], 0, 0, 0);
                h[1][jt] = __builtin_amdgcn_mfma_f32_16x16x32_bf16(A1, B, h[1][jt], 0, 0, 0);
            }
        }
        #pragma unroll
        for (int mt = 0; mt < 2; ++mt)
            #pragma unroll
            for (int jt = 0; jt < 2; ++jt) {
                int j = jt * 16 + l16;
                float sb = sb1[j];
                int rw = rb + mt * 16 + quad * 4;
                #pragma unroll
                for (int r = 0; r < 4; ++r)
                    buf[(rw + r) * LDST + 256 + j] = f2b(fmaxf(h[mt][jt][r] + sb, 0.0f));
            }
    }
    __syncthreads();

    // ---- GEMM3: aw = h1@sw2 (bias added in softmax) ----
    f32x4 aw[2][16];
    #pragma unroll
    for (int mt = 0; mt < 2; ++mt)
        #pragma unroll
        for (int ct = 0; ct < 16; ++ct) aw[mt][ct] = (f32x4){0.f, 0.f, 0.f, 0.f};
    {
        s16x8 A0 = *(const s16x8*)&buf[aoff0 + 256 + quad * 8];
        s16x8 A1 = *(const s16x8*)&buf[aoff1 + 256 + quad * 8];
        const unsigned short* ws2 = ws16 + SW2OFF;
        #pragma unroll
        for (int ct = 0; ct < 16; ++ct) {
            s16x8 B = *(const s16x8*)(ws2 + ((size_t)ct * 64 + lane) * 8);
            aw[0][ct] = __builtin_amdgcn_mfma_f32_16x16x32_bf16(A0, B, aw[0][ct], 0, 0, 0);
            aw[1][ct] = __builtin_amdgcn_mfma_f32_16x16x32_bf16(A1, B, aw[1][ct], 0, 0, 0);
        }
    }

    // ---- softmax over n (per channel), aggregate with vpp ----
    unsigned char vm[2][4];
    #pragma unroll
    for (int mt = 0; mt < 2; ++mt)
        #pragma unroll
        for (int r = 0; r < 4; ++r) vm[mt][r] = visb[rb + mt * 16 + quad * 4 + r];

    float Mf[16], lf[16];
    #pragma unroll
    for (int ct = 0; ct < 16; ++ct) {
        float sb2c = sb2[ct * 16 + l16];
        float ml = -3.0e38f;
        #pragma unroll
        for (int mt = 0; mt < 2; ++mt)
            #pragma unroll
            for (int r = 0; r < 4; ++r) {
                float s = aw[mt][ct][r] + sb2c;
                if (vm[mt][r] == 0) s = -1e9f;
                aw[mt][ct][r] = s;
                ml = fmaxf(ml, s);
            }
        ml = fmaxf(ml, __shfl_xor(ml, 16));
        ml = fmaxf(ml, __shfl_xor(ml, 32));
        if (lane < 16) poolC[wvid * 256 + ct * 16 + lane] = ml;
    }
    __syncthreads();
    #pragma unroll
    for (int ct = 0; ct < 16; ++ct) {
        int col = ct * 16 + l16;
        Mf[ct] = fmaxf(fmaxf(poolC[col], poolC[256 + col]),
                       fmaxf(poolC[512 + col], poolC[768 + col]));
    }
    __syncthreads();
    #pragma unroll
    for (int ct = 0; ct < 16; ++ct) {
        float ls = 0.0f;
        #pragma unroll
        for (int mt = 0; mt < 2; ++mt)
            #pragma unroll
            for (int r = 0; r < 4; ++r) {
                float e = __expf(aw[mt][ct][r] - Mf[ct]);
                aw[mt][ct][r] = e;
                ls += e;
            }
        ls += __shfl_xor(ls, 16);
        ls += __shfl_xor(ls, 32);
        if (lane < 16) poolC[wvid * 256 + ct * 16 + lane] = ls;
    }
    __syncthreads();
    #pragma unroll
    for (int ct = 0; ct < 16; ++ct) {
        int col = ct * 16 + l16;
        lf[ct] = poolC[col] + poolC[256 + col] + poolC[512 + col] + poolC[768 + col];
    }
    __syncthreads();
    #pragma unroll
    for (int ct = 0; ct < 16; ++ct) {
        float as = 0.0f;
        #pragma unroll
        for (int mt = 0; mt < 2; ++mt) {
            unsigned p0 = vppq[mt][ct][0], p1 = vppq[mt][ct][1];
            as = fmaf(aw[mt][ct][0], b2f((unsigned short)p0), as);
            as = fmaf(aw[mt][ct][1], b2f((unsigned short)(p0 >> 16)), as);
            as = fmaf(aw[mt][ct][2], b2f((unsigned short)p1), as);
            as = fmaf(aw[mt][ct][3], b2f((unsigned short)(p1 >> 16)), as);
        }
        as += __shfl_xor(as, 16);
        as += __shfl_xor(as, 32);
        if (lane < 16) poolC[wvid * 256 + ct * 16 + lane] = as;
    }
    __syncthreads();
    float aggv[16];
    #pragma unroll
    for (int ct = 0; ct < 16; ++ct) {
        int col = ct * 16 + l16;
        aggv[ct] = (poolC[col] + poolC[256 + col] + poolC[512 + col] + poolC[768 + col]) / lf[ct];
    }
    __syncthreads();
    if (wvid == 0 && lane < 16) {
        #pragma unroll
        for (int ct = 0; ct < 16; ++ct) poolC[ct * 16 + lane] = aggv[ct];
    }
    __syncthreads();

    // ---- epilogue: xres = agg@Wo + bo + query ----
    const unsigned short* wob = ws16 + WOB_OFF;
    float ao = bo[t];
    for (int k4 = 0; k4 < CC / 4; ++k4) {
        float4 a4 = *(const float4*)&poolC[k4 * 4];
        const unsigned short* w = wob + (size_t)(k4 * 4) * CC + t;
        ao = fmaf(a4.x, b2f(w[0]), ao);
        ao = fmaf(a4.y, b2f(w[CC]), ao);
        ao = fmaf(a4.z, b2f(w[2 * CC]), ao);
        ao = fmaf(a4.w, b2f(w[3 * CC]), ao);
    }
    xres[(size_t)bh * CC + t] = ao + xq;
}

// ---------------- k2: LN2 + FF + residual (4 rows per block) ----------------
__global__ __launch_bounds__(256, 2)
void cft_ff(const float* __restrict__ xres,
            const float* __restrict__ ln2g, const float* __restrict__ ln2b,
            const unsigned short* __restrict__ ws16,
            const float* __restrict__ fb1, const float* __restrict__ fb2,
            float* __restrict__ out)
{
    __shared__ __align__(16) float xr[4][CC];
    __shared__ __align__(16) float xln[4][CC];
    __shared__ __align__(16) float ffh[4][HIDN];
    __shared__ float red[8];
    const int t = threadIdx.x;
    const int b0 = blockIdx.x * 4;
    const unsigned short* fw1b = ws16 + FW1B_OFF;
    const unsigned short* fw2b = ws16 + FW2B_OFF;

    #pragma unroll
    for (int i = 0; i < 4; ++i) xr[i][t] = xres[(size_t)(b0 + i) * CC + t];
    __syncthreads();
    #pragma unroll
    for (int row = 0; row < 4; ++row) {
        float x = xr[row][t];
        float mean = block_sum_256(x, red) * (1.0f / CC);
        float d = x - mean;
        float var = block_sum_256(d * d, red) * (1.0f / CC);
        xln[row][t] = d * rsqrtf(var + EPSL) * ln2g[t] + ln2b[t];
    }
    __syncthreads();
    {
        float acc[4][4];
        #pragma unroll
        for (int rr = 0; rr < 4; ++rr) {
            float b = fb1[t + 256 * rr];
            #pragma unroll
            for (int row = 0; row < 4; ++row) acc[rr][row] = b;
        }
        for (int k4 = 0; k4 < CC / 4; ++k4) {
            float4 xv[4];
            #pragma unroll
            for (int row = 0; row < 4; ++row) xv[row] = *(const float4*)&xln[row][k4 * 4];
            #pragma unroll
            for (int rr = 0; rr < 4; ++rr) {
                const unsigned short* w = fw1b + (size_t)(k4 * 4) * HIDN + t + 256 * rr;
                float w0 = b2f(w[0]), w1 = b2f(w[HIDN]), w2 = b2f(w[2 * HIDN]), w3 = b2f(w[3 * HIDN]);
                #pragma unroll
                for (int row = 0; row < 4; ++row)
                    acc[rr][row] = fmaf(xv[row].x, w0, fmaf(xv[row].y, w1,
                                   fmaf(xv[row].z, w2, fmaf(xv[row].w, w3, acc[rr][row]))));
            }
        }
        #pragma unroll
        for (int rr = 0; rr < 4; ++rr)
            #pragma unroll
            for (int row = 0; row < 4; ++row)
                ffh[row][t + 256 * rr] = fmaxf(acc[rr][row], 0.0f);
    }
    __syncthreads();
    {
        float o[4];
        #pragma unroll
        for (int row = 0; row < 4; ++row) o[row] = xr[row][t] + fb2[t];
        for (int h4 = 0; h4 < HIDN / 4; ++h4) {
            const unsigned short* w = fw2b + (size_t)(h4 * 4) * CC + t;
            float w0 = b2f(w[0]), w1 = b2f(w[CC]), w2 = b2f(w[2 * CC]), w3 = b2f(w[3 * CC]);
            #pragma unroll
            for (int row = 0; row < 4; ++row) {
                float4 hv = *(const float4*)&ffh[row][h4 * 4];
                o[row] = fmaf(hv.x, w0, fmaf(hv.y, w1, fmaf(hv.z, w2, fmaf(hv.w, w3, o[row]))));
            }
        }
        #pragma unroll
        for (int row = 0; row < 4; ++row) out[(size_t)(b0 + row) * CC + t] = o[row];
    }
}

extern "C" void kernel_launch(void* const* d_in, const int* in_sizes, int n_in,
                              void* d_out, int out_size, void* d_ws, size_t ws_size,
                              hipStream_t stream) {
    const float* qin  = (const float*)d_in[0];
    const float* kin  = (const float*)d_in[1];
    const float* rel  = (const float*)d_in[2];
    const int*   vis  = (const int*)  d_in[3];
    const float* ln1g = (const float*)d_in[4];
    const float* ln1b = (const float*)d_in[5];
    const float* ln2g = (const float*)d_in[6];
    const float* ln2b = (const float*)d_in[7];
    const float* Wq   = (const float*)d_in[8];
    const float* Wk   = (const float*)d_in[9];
    const float* Wv   = (const float*)d_in[10];
    const float* pw1  = (const float*)d_in[11];
    const float* pb1  = (const float*)d_in[12];
    const float* pw2  = (const float*)d_in[13];
    const float* pb2  = (const float*)d_in[14];
    const float* sw1  = (const float*)d_in[15];
    const float* sb1  = (const float*)d_in[16];
    const float* sw2  = (const float*)d_in[17];
    const float* sb2  = (const float*)d_in[18];
    const float* Wo   = (const float*)d_in[19];
    const float* bo   = (const float*)d_in[20];
    const float* fw1  = (const float*)d_in[21];
    const float* fb1  = (const float*)d_in[22];
    const float* fw2  = (const float*)d_in[23];
    const float* fb2  = (const float*)d_in[24];
    (void)in_sizes; (void)n_in; (void)out_size; (void)ws_size;

    unsigned short* ws16 = (unsigned short*)d_ws;
    float* xres = (float*)((char*)d_ws + XRES_BYTE_OFF);
    float* o = (float*)d_out;

    prep_frags<<<dim3(NPREP / 256), dim3(256), 0, stream>>>(
        Wk, Wv, pw2, sw1, sw2, fw1, fw2, Wo, ws16);
    cft_attn<<<dim3(1024), dim3(256), 0, stream>>>(
        qin, kin, rel, vis, ln1g, ln1b, Wq, pw1, pb1, pb2, sb1, sb2, bo, ws16, xres);
    cft_ff<<<dim3(256), dim3(256), 0, stream>>>(
        xres, ln2g, ln2b, ws16, fb1, fb2, o);
}

// Round 3
// 498.373 us; speedup vs baseline: 3.5689x; 1.2442x over previous
//
#include <hip/hip_runtime.h>
#include <math.h>

#define NN 128
#define CC 256
#define HIDN 1024
#define KST 264           // key slab row stride (bf16 elems)
#define SST 40            // per-wave strip row stride (bf16 elems)
#define EPSL 1e-6f

typedef short s16x8 __attribute__((ext_vector_type(8)));
typedef float f32x4 __attribute__((ext_vector_type(4)));

// ---- workspace layout (bf16 units) ----
// wk [ct16][kt9][64][8], wv same, sw1 [jt2][kt8][64][8], sw2 [ct16][64][8]
#define WKOFF   0
#define WVOFF   73728
#define SW1OFF  147456
#define SW2OFF  155648
#define NFRAG   163840
#define FW1B_OFF 688128
#define FW2B_OFF 950272
#define WOB_OFF  1212416
#define NPREP   753664

__device__ __forceinline__ unsigned short f2b(float x) {
    unsigned u = __builtin_bit_cast(unsigned, x);
    u += 0x7fffu + ((u >> 16) & 1u);
    return (unsigned short)(u >> 16);
}
__device__ __forceinline__ float b2f(unsigned short s) {
    return __builtin_bit_cast(float, ((unsigned)s) << 16);
}
__device__ __forceinline__ unsigned pack2(float a, float b) {
    return (unsigned)f2b(a) | ((unsigned)f2b(b) << 16);
}
__device__ __forceinline__ float plo(unsigned u) { return b2f((unsigned short)u); }
__device__ __forceinline__ float phi(unsigned u) { return b2f((unsigned short)(u >> 16)); }

__device__ __forceinline__ float block_sum_256(float v, float* red) {
    #pragma unroll
    for (int off = 32; off > 0; off >>= 1)
        v += __shfl_down(v, off, 64);
    const int wid = threadIdx.x >> 6;
    if ((threadIdx.x & 63) == 0) red[wid] = v;
    __syncthreads();
    float s = red[0] + red[1] + red[2] + red[3];
    __syncthreads();
    return s;
}

// ---------------- prep: build bf16 fragment blobs + bf16 weight copies ----------------
__global__ __launch_bounds__(256)
void prep_frags(const float* __restrict__ Wk, const float* __restrict__ Wv,
                const float* __restrict__ pw2, const float* __restrict__ sw1,
                const float* __restrict__ sw2, const float* __restrict__ fw1,
                const float* __restrict__ fw2, const float* __restrict__ Wo,
                unsigned short* __restrict__ ws16)
{
    int e = blockIdx.x * 256 + threadIdx.x;
    if (e >= NPREP) return;
    if (e < NFRAG) {
        float val;
        if (e < SW1OFF) {  // wk or wv blob (with pw2 as kt==8)
            const float* W = (e < WVOFF) ? Wk : Wv;
            int local = (e < WVOFF) ? e : e - WVOFF;
            int ct = local / 4608;
            int rem = local % 4608;
            int kt = rem / 512;
            int l = (rem % 512) / 8;
            int j = rem % 8;
            int k = kt * 32 + (l >> 4) * 8 + j;
            int col = ct * 16 + (l & 15);
            val = (kt < 8) ? W[k * CC + col] : pw2[(k - 256) * CC + col];
        } else if (e < SW2OFF) {
            int local = e - SW1OFF;
            int jt = local / 4096;
            int rem = local % 4096;
            int kt = rem / 512;
            int l = (rem % 512) / 8;
            int j = rem % 8;
            int k = kt * 32 + (l >> 4) * 8 + j;
            val = sw1[k * 32 + jt * 16 + (l & 15)];
        } else {
            int local = e - SW2OFF;
            int ct = local / 512;
            int l = (local % 512) / 8;
            int j = local % 8;
            int k = (l >> 4) * 8 + j;
            val = sw2[k * CC + ct * 16 + (l & 15)];
        }
        ws16[e] = f2b(val);
    } else if (e < NFRAG + 262144) {
        int i = e - NFRAG;
        ws16[FW1B_OFF + i] = f2b(fw1[i]);
    } else if (e < NFRAG + 524288) {
        int i = e - NFRAG - 262144;
        ws16[FW2B_OFF + i] = f2b(fw2[i]);
    } else {
        int i = e - NFRAG - 524288;
        ws16[WOB_OFF + i] = f2b(Wo[i]);
    }
}

// ---------------- fused attention + FF (one block per (b,h)) ----------------
// LDS map (bytes):
//   [0,67584)       keys bf16 128 x KST
//   [67584,77824)   per-wave strips (32 x SST bf16, 2560 B each)  -- overlays:
//       poolC f32[1024] at 67584, ffh f32[1024] at 71680
//   [77824,78848)   poolA f32[256]  (xln -> qm -> agg -> xln2)
//   [78848,79872)   poolB f32[256]  (pb2)
//   [79872,80000)   visb
//   [80000,80032)   red
__global__ __launch_bounds__(256, 2)
void cft_attn(const float* __restrict__ qin, const float* __restrict__ kin,
              const float* __restrict__ rel, const int* __restrict__ vis,
              const float* __restrict__ ln1g, const float* __restrict__ ln1b,
              const float* __restrict__ ln2g, const float* __restrict__ ln2b,
              const float* __restrict__ Wq,
              const float* __restrict__ pw1, const float* __restrict__ pb1,
              const float* __restrict__ pb2,
              const float* __restrict__ sb1, const float* __restrict__ sb2,
              const float* __restrict__ bo,
              const float* __restrict__ fb1, const float* __restrict__ fb2,
              const unsigned short* __restrict__ ws16,
              float* __restrict__ out)
{
    __shared__ __align__(16) unsigned char smem[80064];
    unsigned short* keyb = (unsigned short*)smem;
    float* poolC = (float*)(smem + 67584);
    float* ffh   = (float*)(smem + 71680);
    float* poolA = (float*)(smem + 77824);
    float* poolB = (float*)(smem + 78848);
    unsigned char* visb = smem + 79872;
    float* red   = (float*)(smem + 80000);

    const int bh = blockIdx.x;
    const int t = threadIdx.x;
    const int lane = t & 63;
    const int wvid = t >> 6;
    const int quad = lane >> 4;
    const int l16 = lane & 15;
    const int rb = wvid * 32;
    unsigned short* strip = (unsigned short*)(smem + 67584) + wvid * 1280;

    // ---- stage keys -> bf16 LDS ----
    const float4* kb4 = (const float4*)(kin + (size_t)bh * NN * CC);
    #pragma unroll
    for (int i = 0; i < 32; ++i) {
        int flat = i * 256 + t;
        int row = flat >> 6;
        int cu = flat & 63;
        float4 kv = kb4[flat];
        uint2 pk;
        pk.x = pack2(kv.x, kv.y);
        pk.y = pack2(kv.z, kv.w);
        *(uint2*)&keyb[row * KST + cu * 4] = pk;
    }
    if (t < NN) visb[t] = (unsigned char)(vis[(size_t)bh * NN + t] != 0);
    poolB[t] = pb2[t];

    // ---- pos-MLP A-fragments in registers (kt==8 of GEMM1) ----
    union { s16x8 v; unsigned short u[8]; } phf0, phf1;
    {
        const int row0 = rb + l16, row1 = rb + 16 + l16;
        float4 r40 = *(const float4*)(rel + ((size_t)bh * NN + row0) * 4);
        float4 r41 = *(const float4*)(rel + ((size_t)bh * NN + row1) * 4);
        #pragma unroll
        for (int j = 0; j < 8; ++j) {
            int col = quad * 8 + j;
            float w0 = pw1[col], w1 = pw1[32 + col], w2 = pw1[64 + col], w3 = pw1[96 + col];
            float b = pb1[col];
            float v0 = fmaf(r40.x, w0, fmaf(r40.y, w1, fmaf(r40.z, w2, fmaf(r40.w, w3, b))));
            float v1 = fmaf(r41.x, w0, fmaf(r41.y, w1, fmaf(r41.z, w2, fmaf(r41.w, w3, b))));
            phf0.u[j] = f2b(fmaxf(v0, 0.0f));
            phf1.u[j] = f2b(fmaxf(v1, 0.0f));
        }
    }

    // ---- LN1 + q matvec -> qm = pb2 - q into poolA ----
    const float xq = qin[(size_t)bh * CC + t];
    float mean = block_sum_256(xq, red) * (1.0f / CC);
    float dd = xq - mean;
    float var = block_sum_256(dd * dd, red) * (1.0f / CC);
    poolA[t] = dd * rsqrtf(var + EPSL) * ln1g[t] + ln1b[t];
    __syncthreads();
    float qv = 0.0f;
    for (int k4 = 0; k4 < CC / 4; ++k4) {
        float4 xv = *(const float4*)&poolA[k4 * 4];
        const float* w = Wq + (size_t)(k4 * 4) * CC + t;
        qv = fmaf(xv.x, w[0], qv);
        qv = fmaf(xv.y, w[CC], qv);
        qv = fmaf(xv.z, w[2 * CC], qv);
        qv = fmaf(xv.w, w[3 * CC], qv);
    }
    __syncthreads();
    poolA[t] = poolB[t] - qv;   // qm = pb2 - q
    __syncthreads();

    const int aoff0 = (rb + l16) * KST;
    const int aoff1 = (rb + 16 + l16) * KST;
    const unsigned short* wsk = ws16 + WKOFF;
    const unsigned short* wsv = ws16 + WVOFF;
    const unsigned short* ws1 = ws16 + SW1OFF;
    const unsigned short* ws2 = ws16 + SW2OFF;

    // ---- pass 1: GEMM1-K (attn chunks) interleaved with GEMM2 (h1 acc) ----
    f32x4 hacc[2][2];
    #pragma unroll
    for (int mt = 0; mt < 2; ++mt)
        #pragma unroll
        for (int jt = 0; jt < 2; ++jt) hacc[mt][jt] = (f32x4){0.f, 0.f, 0.f, 0.f};

    for (int ck = 0; ck < 8; ++ck) {
        f32x4 acc[2][2];
        #pragma unroll
        for (int mt = 0; mt < 2; ++mt)
            #pragma unroll
            for (int ctl = 0; ctl < 2; ++ctl) acc[mt][ctl] = (f32x4){0.f, 0.f, 0.f, 0.f};
        #pragma unroll
        for (int kt = 0; kt < 8; ++kt) {
            s16x8 A0 = *(const s16x8*)&keyb[aoff0 + kt * 32 + quad * 8];
            s16x8 A1 = *(const s16x8*)&keyb[aoff1 + kt * 32 + quad * 8];
            #pragma unroll
            for (int ctl = 0; ctl < 2; ++ctl) {
                s16x8 B = *(const s16x8*)(wsk + ((size_t)((ck * 2 + ctl) * 9 + kt) * 512) + lane * 8);
                acc[0][ctl] = __builtin_amdgcn_mfma_f32_16x16x32_bf16(A0, B, acc[0][ctl], 0, 0, 0);
                acc[1][ctl] = __builtin_amdgcn_mfma_f32_16x16x32_bf16(A1, B, acc[1][ctl], 0, 0, 0);
            }
        }
        #pragma unroll
        for (int ctl = 0; ctl < 2; ++ctl) {   // kt == 8: pos fragment
            s16x8 B = *(const s16x8*)(wsk + ((size_t)((ck * 2 + ctl) * 9 + 8) * 512) + lane * 8);
            acc[0][ctl] = __builtin_amdgcn_mfma_f32_16x16x32_bf16(phf0.v, B, acc[0][ctl], 0, 0, 0);
            acc[1][ctl] = __builtin_amdgcn_mfma_f32_16x16x32_bf16(phf1.v, B, acc[1][ctl], 0, 0, 0);
        }
        // add qm, write bf16 chunk to own strip (C layout)
        #pragma unroll
        for (int ctl = 0; ctl < 2; ++ctl) {
            float qm = poolA[(ck * 2 + ctl) * 16 + l16];
            #pragma unroll
            for (int mt = 0; mt < 2; ++mt) {
                int rw = (mt * 16 + quad * 4) * SST + ctl * 16 + l16;
                strip[rw]           = f2b(acc[mt][ctl][0] + qm);
                strip[rw + SST]     = f2b(acc[mt][ctl][1] + qm);
                strip[rw + 2 * SST] = f2b(acc[mt][ctl][2] + qm);
                strip[rw + 3 * SST] = f2b(acc[mt][ctl][3] + qm);
            }
        }
        // GEMM2 partial (kt = ck), A from own strip
        {
            s16x8 A0 = *(const s16x8*)&strip[l16 * SST + quad * 8];
            s16x8 A1 = *(const s16x8*)&strip[(16 + l16) * SST + quad * 8];
            #pragma unroll
            for (int jt = 0; jt < 2; ++jt) {
                s16x8 B = *(const s16x8*)(ws1 + ((size_t)(jt * 8 + ck) * 64 + lane) * 8);
                hacc[0][jt] = __builtin_amdgcn_mfma_f32_16x16x32_bf16(A0, B, hacc[0][jt], 0, 0, 0);
                hacc[1][jt] = __builtin_amdgcn_mfma_f32_16x16x32_bf16(A1, B, hacc[1][jt], 0, 0, 0);
            }
        }
    }

    // ---- h1 = relu(hacc + sb1) -> strip ----
    #pragma unroll
    for (int mt = 0; mt < 2; ++mt)
        #pragma unroll
        for (int jt = 0; jt < 2; ++jt) {
            float sb = sb1[jt * 16 + l16];
            int rw = (mt * 16 + quad * 4) * SST + jt * 16 + l16;
            strip[rw]           = f2b(fmaxf(hacc[mt][jt][0] + sb, 0.0f));
            strip[rw + SST]     = f2b(fmaxf(hacc[mt][jt][1] + sb, 0.0f));
            strip[rw + 2 * SST] = f2b(fmaxf(hacc[mt][jt][2] + sb, 0.0f));
            strip[rw + 3 * SST] = f2b(fmaxf(hacc[mt][jt][3] + sb, 0.0f));
        }

    // ---- GEMM3: scores (masked, packed bf16 in regs) ----
    unsigned char vm[2][4];
    #pragma unroll
    for (int mt = 0; mt < 2; ++mt)
        #pragma unroll
        for (int r = 0; r < 4; ++r) vm[mt][r] = visb[rb + mt * 16 + quad * 4 + r];

    unsigned scoresq[16][2][2];
    float mloc[16];
    {
        s16x8 A0 = *(const s16x8*)&strip[l16 * SST + quad * 8];
        s16x8 A1 = *(const s16x8*)&strip[(16 + l16) * SST + quad * 8];
        #pragma unroll
        for (int ct = 0; ct < 16; ++ct) {
            f32x4 a0 = (f32x4){0.f, 0.f, 0.f, 0.f};
            f32x4 a1 = (f32x4){0.f, 0.f, 0.f, 0.f};
            s16x8 B = *(const s16x8*)(ws2 + ((size_t)ct * 64 + lane) * 8);
            a0 = __builtin_amdgcn_mfma_f32_16x16x32_bf16(A0, B, a0, 0, 0, 0);
            a1 = __builtin_amdgcn_mfma_f32_16x16x32_bf16(A1, B, a1, 0, 0, 0);
            float sb2c = sb2[ct * 16 + l16];
            float s0[4], s1[4];
            float ml = -3.0e38f;
            #pragma unroll
            for (int r = 0; r < 4; ++r) {
                s0[r] = vm[0][r] ? (a0[r] + sb2c) : -1e9f;
                s1[r] = vm[1][r] ? (a1[r] + sb2c) : -1e9f;
                ml = fmaxf(ml, fmaxf(s0[r], s1[r]));
            }
            scoresq[ct][0][0] = pack2(s0[0], s0[1]);
            scoresq[ct][0][1] = pack2(s0[2], s0[3]);
            scoresq[ct][1][0] = pack2(s1[0], s1[1]);
            scoresq[ct][1][1] = pack2(s1[2], s1[3]);
            mloc[ct] = ml;
        }
    }
    __syncthreads();   // strips (incl. waves 0/1 under poolC) now dead

    // ---- softmax: global max per channel ----
    #pragma unroll
    for (int ct = 0; ct < 16; ++ct) {
        float m = mloc[ct];
        m = fmaxf(m, __shfl_xor(m, 16));
        m = fmaxf(m, __shfl_xor(m, 32));
        if (lane < 16) poolC[wvid * 256 + ct * 16 + lane] = m;
    }
    __syncthreads();
    float Mf[16];
    #pragma unroll
    for (int ct = 0; ct < 16; ++ct) {
        int col = ct * 16 + l16;
        Mf[ct] = fmaxf(fmaxf(poolC[col], poolC[256 + col]),
                       fmaxf(poolC[512 + col], poolC[768 + col]));
    }
    __syncthreads();

    // ---- exp pass: scoresq := packed exp(s - M); partial l sums ----
    #pragma unroll
    for (int ct = 0; ct < 16; ++ct) {
        float ls = 0.0f;
        #pragma unroll
        for (int mt = 0; mt < 2; ++mt)
            #pragma unroll
            for (int i = 0; i < 2; ++i) {
                unsigned p = scoresq[ct][mt][i];
                float e0 = __expf(plo(p) - Mf[ct]);
                float e1 = __expf(phi(p) - Mf[ct]);
                scoresq[ct][mt][i] = pack2(e0, e1);
                ls += e0 + e1;
            }
        ls += __shfl_xor(ls, 16);
        ls += __shfl_xor(ls, 32);
        if (lane < 16) poolC[wvid * 256 + ct * 16 + lane] = ls;
    }
    __syncthreads();
    float lf[16];
    #pragma unroll
    for (int ct = 0; ct < 16; ++ct) {
        int col = ct * 16 + l16;
        lf[ct] = poolC[col] + poolC[256 + col] + poolC[512 + col] + poolC[768 + col];
    }

    // ---- pass 2: GEMM1-V chunk-wise, fused weighted aggregation ----
    float aggp[16];
    #pragma unroll
    for (int ct = 0; ct < 16; ++ct) aggp[ct] = 0.0f;

    #pragma unroll
    for (int ck = 0; ck < 8; ++ck) {
        f32x4 acc[2][2];
        #pragma unroll
        for (int mt = 0; mt < 2; ++mt)
            #pragma unroll
            for (int ctl = 0; ctl < 2; ++ctl) acc[mt][ctl] = (f32x4){0.f, 0.f, 0.f, 0.f};
        #pragma unroll
        for (int kt = 0; kt < 8; ++kt) {
            s16x8 A0 = *(const s16x8*)&keyb[aoff0 + kt * 32 + quad * 8];
            s16x8 A1 = *(const s16x8*)&keyb[aoff1 + kt * 32 + quad * 8];
            #pragma unroll
            for (int ctl = 0; ctl < 2; ++ctl) {
                s16x8 B = *(const s16x8*)(wsv + ((size_t)((ck * 2 + ctl) * 9 + kt) * 512) + lane * 8);
                acc[0][ctl] = __builtin_amdgcn_mfma_f32_16x16x32_bf16(A0, B, acc[0][ctl], 0, 0, 0);
                acc[1][ctl] = __builtin_amdgcn_mfma_f32_16x16x32_bf16(A1, B, acc[1][ctl], 0, 0, 0);
            }
        }
        #pragma unroll
        for (int ctl = 0; ctl < 2; ++ctl) {
            s16x8 B = *(const s16x8*)(wsv + ((size_t)((ck * 2 + ctl) * 9 + 8) * 512) + lane * 8);
            acc[0][ctl] = __builtin_amdgcn_mfma_f32_16x16x32_bf16(phf0.v, B, acc[0][ctl], 0, 0, 0);
            acc[1][ctl] = __builtin_amdgcn_mfma_f32_16x16x32_bf16(phf1.v, B, acc[1][ctl], 0, 0, 0);
        }
        #pragma unroll
        for (int ctl = 0; ctl < 2; ++ctl) {
            const int ct = ck * 2 + ctl;
            float pb = poolB[ct * 16 + l16];
            float a = aggp[ct];
            #pragma unroll
            for (int mt = 0; mt < 2; ++mt) {
                unsigned p0 = scoresq[ct][mt][0], p1 = scoresq[ct][mt][1];
                a = fmaf(plo(p0), acc[mt][ctl][0] + pb, a);
                a = fmaf(phi(p0), acc[mt][ctl][1] + pb, a);
                a = fmaf(plo(p1), acc[mt][ctl][2] + pb, a);
                a = fmaf(phi(p1), acc[mt][ctl][3] + pb, a);
            }
            aggp[ct] = a;
        }
    }
    __syncthreads();   // lf reads done everywhere before poolC overwrite
    #pragma unroll
    for (int ct = 0; ct < 16; ++ct) {
        float a = aggp[ct];
        a += __shfl_xor(a, 16);
        a += __shfl_xor(a, 32);
        if (lane < 16) poolC[wvid * 256 + ct * 16 + lane] = a;
    }
    __syncthreads();
    if (wvid == 0 && lane < 16) {
        #pragma unroll
        for (int ct = 0; ct < 16; ++ct) {
            int col = ct * 16 + lane;
            float a = poolC[col] + poolC[256 + col] + poolC[512 + col] + poolC[768 + col];
            poolA[col] = a / lf[ct];
        }
    }
    __syncthreads();

    // ---- epilogue 1: xres = agg@Wo + bo + query ----
    const unsigned short* wob = ws16 + WOB_OFF;
    float ao = bo[t];
    for (int k4 = 0; k4 < CC / 4; ++k4) {
        float4 a4 = *(const float4*)&poolA[k4 * 4];
        const unsigned short* w = wob + (size_t)(k4 * 4) * CC + t;
        ao = fmaf(a4.x, b2f(w[0]), ao);
        ao = fmaf(a4.y, b2f(w[CC]), ao);
        ao = fmaf(a4.z, b2f(w[2 * CC]), ao);
        ao = fmaf(a4.w, b2f(w[3 * CC]), ao);
    }
    const float xrs = ao + xq;

    // ---- epilogue 2: LN2 + FF + residual ----
    float mean2 = block_sum_256(xrs, red) * (1.0f / CC);
    float d2 = xrs - mean2;
    float var2 = block_sum_256(d2 * d2, red) * (1.0f / CC);
    float yn = d2 * rsqrtf(var2 + EPSL) * ln2g[t] + ln2b[t];
    poolA[t] = yn;
    __syncthreads();

    const unsigned short* fw1b = ws16 + FW1B_OFF;
    const unsigned short* fw2b = ws16 + FW2B_OFF;
    #pragma unroll
    for (int rr = 0; rr < 4; ++rr) {
        const int hh = t + 256 * rr;
        float hv = fb1[hh];
        for (int k4 = 0; k4 < CC / 4; ++k4) {
            float4 xv = *(const float4*)&poolA[k4 * 4];
            const unsigned short* w = fw1b + (size_t)(k4 * 4) * HIDN + hh;
            hv = fmaf(xv.x, b2f(w[0]), hv);
            hv = fmaf(xv.y, b2f(w[HIDN]), hv);
            hv = fmaf(xv.z, b2f(w[2 * HIDN]), hv);
            hv = fmaf(xv.w, b2f(w[3 * HIDN]), hv);
        }
        ffh[hh] = fmaxf(hv, 0.0f);
    }
    __syncthreads();

    float o = xrs + fb2[t];
    for (int h4 = 0; h4 < HIDN / 4; ++h4) {
        float4 hv4 = *(const float4*)&ffh[h4 * 4];
        const unsigned short* w = fw2b + (size_t)(h4 * 4) * CC + t;
        o = fmaf(hv4.x, b2f(w[0]), o);
        o = fmaf(hv4.y, b2f(w[CC]), o);
        o = fmaf(hv4.z, b2f(w[2 * CC]), o);
        o = fmaf(hv4.w, b2f(w[3 * CC]), o);
    }
    out[(size_t)bh * CC + t] = o;
}

extern "C" void kernel_launch(void* const* d_in, const int* in_sizes, int n_in,
                              void* d_out, int out_size, void* d_ws, size_t ws_size,
                              hipStream_t stream) {
    const float* qin  = (const float*)d_in[0];
    const float* kin  = (const float*)d_in[1];
    const float* rel  = (const float*)d_in[2];
    const int*   vis  = (const int*)  d_in[3];
    const float* ln1g = (const float*)d_in[4];
    const float* ln1b = (const float*)d_in[5];
    const float* ln2g = (const float*)d_in[6];
    const float* ln2b = (const float*)d_in[7];
    const float* Wq   = (const float*)d_in[8];
    const float* Wk   = (const float*)d_in[9];
    const float* Wv   = (const float*)d_in[10];
    const float* pw1  = (const float*)d_in[11];
    const float* pb1  = (const float*)d_in[12];
    const float* pw2  = (const float*)d_in[13];
    const float* pb2  = (const float*)d_in[14];
    const float* sw1  = (const float*)d_in[15];
    const float* sb1  = (const float*)d_in[16];
    const float* sw2  = (const float*)d_in[17];
    const float* sb2  = (const float*)d_in[18];
    const float* Wo   = (const float*)d_in[19];
    const float* bo   = (const float*)d_in[20];
    const float* fw1  = (const float*)d_in[21];
    const float* fb1  = (const float*)d_in[22];
    const float* fw2  = (const float*)d_in[23];
    const float* fb2  = (const float*)d_in[24];
    (void)in_sizes; (void)n_in; (void)out_size; (void)ws_size;

    unsigned short* ws16 = (unsigned short*)d_ws;
    float* o = (float*)d_out;

    prep_frags<<<dim3(NPREP / 256), dim3(256), 0, stream>>>(
        Wk, Wv, pw2, sw1, sw2, fw1, fw2, Wo, ws16);
    cft_attn<<<dim3(1024), dim3(256), 0, stream>>>(
        qin, kin, rel, vis, ln1g, ln1b, ln2g, ln2b, Wq, pw1, pb1, pb2,
        sb1, sb2, bo, fb1, fb2, ws16, o);
}

// Round 4
// 445.185 us; speedup vs baseline: 3.9952x; 1.1195x over previous
//
#include <hip/hip_runtime.h>
#include <math.h>

#define NN 128
#define CC 256
#define HIDN 1024
#define KST 264           // key slab row stride (bf16 elems), 16B-aligned rows
#define SST 40            // per-wave strip row stride (bf16 elems), 16B-aligned rows
#define EPSL 1e-6f

typedef short s16x8 __attribute__((ext_vector_type(8)));
typedef float f32x4 __attribute__((ext_vector_type(4)));

// ---- workspace layout (bf16 units) ----
// wk [ct16][kt9][64][8], wv same, sw1 [jt2][kt8][64][8], sw2 [ct16][64][8]
#define WKOFF   0
#define WVOFF   73728
#define SW1OFF  147456
#define SW2OFF  155648
#define NFRAG   163840
#define FW1B_OFF 688128
#define FW2B_OFF 950272
#define WOB_OFF  1212416
#define NPREP   753664

__device__ __forceinline__ unsigned short f2b(float x) {
    unsigned u = __builtin_bit_cast(unsigned, x);
    u += 0x7fffu + ((u >> 16) & 1u);
    return (unsigned short)(u >> 16);
}
__device__ __forceinline__ float b2f(unsigned short s) {
    return __builtin_bit_cast(float, ((unsigned)s) << 16);
}
__device__ __forceinline__ unsigned pack2(float a, float b) {
    return (unsigned)f2b(a) | ((unsigned)f2b(b) << 16);
}

__device__ __forceinline__ float block_sum_256(float v, float* red) {
    #pragma unroll
    for (int off = 32; off > 0; off >>= 1)
        v += __shfl_down(v, off, 64);
    const int wid = threadIdx.x >> 6;
    if ((threadIdx.x & 63) == 0) red[wid] = v;
    __syncthreads();
    float s = red[0] + red[1] + red[2] + red[3];
    __syncthreads();
    return s;
}

// ---------------- prep: source-linear (coalesced reads, scattered 2B writes) ----------------
// e sections: [0,131072) Wk/Wv -> blobs; [131072,147456) pw2 -> wk/wv kt8;
// [147456,155648) sw1; [155648,163840) sw2; then fw1/fw2/Wo bf16 copies.
__global__ __launch_bounds__(256)
void prep_frags(const float* __restrict__ Wk, const float* __restrict__ Wv,
                const float* __restrict__ pw2, const float* __restrict__ sw1,
                const float* __restrict__ sw2, const float* __restrict__ fw1,
                const float* __restrict__ fw2, const float* __restrict__ Wo,
                unsigned short* __restrict__ ws16)
{
    int e = blockIdx.x * 256 + threadIdx.x;
    if (e >= NPREP) return;
    if (e < 131072) {
        int sec = e >> 16;
        int i = e & 65535;
        const float* W = sec ? Wv : Wk;
        int base = sec ? WVOFF : WKOFF;
        int k = i >> 8, col = i & 255;
        int dest = (col >> 4) * 4608 + (k >> 5) * 512
                 + ((((k >> 3) & 3) << 4) + (col & 15)) * 8 + (k & 7);
        ws16[base + dest] = f2b(W[i]);
    } else if (e < 147456) {
        int r = e - 131072;
        int sec = r >> 13;
        int i = r & 8191;
        int kp = i >> 8, col = i & 255;
        int base = sec ? WVOFF : WKOFF;
        int dest = (col >> 4) * 4608 + 8 * 512
                 + ((((kp >> 3) & 3) << 4) + (col & 15)) * 8 + (kp & 7);
        ws16[base + dest] = f2b(pw2[i]);
    } else if (e < 155648) {
        int i = e - 147456;
        int k = i >> 5, col = i & 31;
        int dest = (col >> 4) * 4096 + (k >> 5) * 512
                 + ((((k >> 3) & 3) << 4) + (col & 15)) * 8 + (k & 7);
        ws16[SW1OFF + dest] = f2b(sw1[i]);
    } else if (e < 163840) {
        int i = e - 155648;
        int k = i >> 8, col = i & 255;
        int dest = (col >> 4) * 512
                 + ((((k >> 3) & 3) << 4) + (col & 15)) * 8 + (k & 7);
        ws16[SW2OFF + dest] = f2b(sw2[i]);
    } else if (e < 425984) {
        int i = e - 163840; ws16[FW1B_OFF + i] = f2b(fw1[i]);
    } else if (e < 688128) {
        int i = e - 425984; ws16[FW2B_OFF + i] = f2b(fw2[i]);
    } else {
        int i = e - 688128; ws16[WOB_OFF + i] = f2b(Wo[i]);
    }
}

// ---------------- fused attention + FF (one block per (b,h)) ----------------
// LDS map (bytes):
//   [0,67584)       keys bf16 128 x KST          (dead after phase 2 -> overlays)
//   [67584,77824)   per-wave strips 32 x SST bf16 (h1 lives here through phase 2)
//   [77824,78848)   poolA f32[256]  (xln -> qm -> Mmax -> agg -> xln2)
//   [78848,79872)   poolB f32[256]  (pb2)
//   [79872,80000)   visb
//   [80000,80032)   red
// overlays on keys after phase 2: aggpool f32[1024] @0, lpool f32[1024] @4096, ffh f32[1024] @8192
__global__ __launch_bounds__(256, 2)
void cft_attn(const float* __restrict__ qin, const float* __restrict__ kin,
              const float* __restrict__ rel, const int* __restrict__ vis,
              const float* __restrict__ ln1g, const float* __restrict__ ln1b,
              const float* __restrict__ ln2g, const float* __restrict__ ln2b,
              const float* __restrict__ Wq,
              const float* __restrict__ pw1, const float* __restrict__ pb1,
              const float* __restrict__ pb2,
              const float* __restrict__ sb1, const float* __restrict__ sb2,
              const float* __restrict__ bo,
              const float* __restrict__ fb1, const float* __restrict__ fb2,
              const unsigned short* __restrict__ ws16,
              float* __restrict__ out)
{
    __shared__ __align__(16) unsigned char smem[80032];
    unsigned short* keyb = (unsigned short*)smem;
    float* poolA = (float*)(smem + 77824);
    float* poolB = (float*)(smem + 78848);
    unsigned char* visb = smem + 79872;
    float* red   = (float*)(smem + 80000);
    float* aggpool = (float*)smem;
    float* lpool   = (float*)(smem + 4096);
    float* ffh     = (float*)(smem + 8192);

    const int bh = blockIdx.x;
    const int t = threadIdx.x;
    const int lane = t & 63;
    const int wvid = t >> 6;
    const int quad = lane >> 4;
    const int l16 = lane & 15;
    const int rb = wvid * 32;
    unsigned short* strip = (unsigned short*)(smem + 67584) + wvid * (32 * SST);

    // ---- stage keys -> bf16 LDS ----
    const float4* kb4 = (const float4*)(kin + (size_t)bh * NN * CC);
    #pragma unroll
    for (int i = 0; i < 32; ++i) {
        int flat = i * 256 + t;
        int row = flat >> 6;
        int cu = flat & 63;
        float4 kv = kb4[flat];
        uint2 pk;
        pk.x = pack2(kv.x, kv.y);
        pk.y = pack2(kv.z, kv.w);
        *(uint2*)&keyb[row * KST + cu * 4] = pk;
    }
    if (t < NN) visb[t] = (unsigned char)(vis[(size_t)bh * NN + t] != 0);
    poolB[t] = pb2[t];

    // ---- pos-MLP A-fragments in registers (kt==8 of GEMM1) ----
    union { s16x8 v; unsigned short u[8]; } phf0, phf1;
    {
        const int row0 = rb + l16, row1 = rb + 16 + l16;
        float4 r40 = *(const float4*)(rel + ((size_t)bh * NN + row0) * 4);
        float4 r41 = *(const float4*)(rel + ((size_t)bh * NN + row1) * 4);
        #pragma unroll
        for (int j = 0; j < 8; ++j) {
            int col = quad * 8 + j;
            float w0 = pw1[col], w1 = pw1[32 + col], w2 = pw1[64 + col], w3 = pw1[96 + col];
            float b = pb1[col];
            float v0 = fmaf(r40.x, w0, fmaf(r40.y, w1, fmaf(r40.z, w2, fmaf(r40.w, w3, b))));
            float v1 = fmaf(r41.x, w0, fmaf(r41.y, w1, fmaf(r41.z, w2, fmaf(r41.w, w3, b))));
            phf0.u[j] = f2b(fmaxf(v0, 0.0f));
            phf1.u[j] = f2b(fmaxf(v1, 0.0f));
        }
    }

    // ---- LN1 + q matvec -> qm = pb2 - q into poolA ----
    const float xq = qin[(size_t)bh * CC + t];
    float mean = block_sum_256(xq, red) * (1.0f / CC);
    float dd = xq - mean;
    float var = block_sum_256(dd * dd, red) * (1.0f / CC);
    poolA[t] = dd * rsqrtf(var + EPSL) * ln1g[t] + ln1b[t];
    __syncthreads();
    float qv = 0.0f;
    for (int k4 = 0; k4 < CC / 4; ++k4) {
        float4 xv = *(const float4*)&poolA[k4 * 4];
        const float* w = Wq + (size_t)(k4 * 4) * CC + t;
        qv = fmaf(xv.x, w[0], qv);
        qv = fmaf(xv.y, w[CC], qv);
        qv = fmaf(xv.z, w[2 * CC], qv);
        qv = fmaf(xv.w, w[3 * CC], qv);
    }
    __syncthreads();
    poolA[t] = poolB[t] - qv;   // qm = pb2 - q
    __syncthreads();

    const int aoff0 = (rb + l16) * KST;
    const int aoff1 = (rb + 16 + l16) * KST;
    const unsigned short* wsk = ws16 + WKOFF;
    const unsigned short* wsv = ws16 + WVOFF;
    const unsigned short* ws1 = ws16 + SW1OFF;
    const unsigned short* ws2 = ws16 + SW2OFF;

    unsigned char vm[2][4];
    #pragma unroll
    for (int mt = 0; mt < 2; ++mt)
        #pragma unroll
        for (int r = 0; r < 4; ++r) vm[mt][r] = visb[rb + mt * 16 + quad * 4 + r];

    // ---- phase 1: attn chunks (GEMM1-K) interleaved with GEMM2 (h1 acc) ----
    f32x4 hacc[2][2];
    #pragma unroll
    for (int mt = 0; mt < 2; ++mt)
        #pragma unroll
        for (int jt = 0; jt < 2; ++jt) hacc[mt][jt] = (f32x4){0.f, 0.f, 0.f, 0.f};

    #pragma unroll 1
    for (int ck = 0; ck < 8; ++ck) {
        f32x4 acc[2][2];
        #pragma unroll
        for (int mt = 0; mt < 2; ++mt)
            #pragma unroll
            for (int ctl = 0; ctl < 2; ++ctl) acc[mt][ctl] = (f32x4){0.f, 0.f, 0.f, 0.f};
        #pragma unroll
        for (int kt = 0; kt < 8; ++kt) {
            s16x8 A0 = *(const s16x8*)&keyb[aoff0 + kt * 32 + quad * 8];
            s16x8 A1 = *(const s16x8*)&keyb[aoff1 + kt * 32 + quad * 8];
            #pragma unroll
            for (int ctl = 0; ctl < 2; ++ctl) {
                s16x8 B = *(const s16x8*)(wsk + ((size_t)((ck * 2 + ctl) * 9 + kt) * 512) + lane * 8);
                acc[0][ctl] = __builtin_amdgcn_mfma_f32_16x16x32_bf16(A0, B, acc[0][ctl], 0, 0, 0);
                acc[1][ctl] = __builtin_amdgcn_mfma_f32_16x16x32_bf16(A1, B, acc[1][ctl], 0, 0, 0);
            }
        }
        #pragma unroll
        for (int ctl = 0; ctl < 2; ++ctl) {   // kt == 8: pos fragment
            s16x8 B = *(const s16x8*)(wsk + ((size_t)((ck * 2 + ctl) * 9 + 8) * 512) + lane * 8);
            acc[0][ctl] = __builtin_amdgcn_mfma_f32_16x16x32_bf16(phf0.v, B, acc[0][ctl], 0, 0, 0);
            acc[1][ctl] = __builtin_amdgcn_mfma_f32_16x16x32_bf16(phf1.v, B, acc[1][ctl], 0, 0, 0);
        }
        #pragma unroll
        for (int ctl = 0; ctl < 2; ++ctl) {
            float qm = poolA[(ck * 2 + ctl) * 16 + l16];
            #pragma unroll
            for (int mt = 0; mt < 2; ++mt) {
                int rw = (mt * 16 + quad * 4) * SST + ctl * 16 + l16;
                strip[rw]           = f2b(acc[mt][ctl][0] + qm);
                strip[rw + SST]     = f2b(acc[mt][ctl][1] + qm);
                strip[rw + 2 * SST] = f2b(acc[mt][ctl][2] + qm);
                strip[rw + 3 * SST] = f2b(acc[mt][ctl][3] + qm);
            }
        }
        {
            s16x8 A0 = *(const s16x8*)&strip[l16 * SST + quad * 8];
            s16x8 A1 = *(const s16x8*)&strip[(16 + l16) * SST + quad * 8];
            #pragma unroll
            for (int jt = 0; jt < 2; ++jt) {
                s16x8 B = *(const s16x8*)(ws1 + ((size_t)(jt * 8 + ck) * 64 + lane) * 8);
                hacc[0][jt] = __builtin_amdgcn_mfma_f32_16x16x32_bf16(A0, B, hacc[0][jt], 0, 0, 0);
                hacc[1][jt] = __builtin_amdgcn_mfma_f32_16x16x32_bf16(A1, B, hacc[1][jt], 0, 0, 0);
            }
        }
    }

    // ---- h1 = relu(hacc + sb1) -> strip (stays live through phase 2) ----
    #pragma unroll
    for (int mt = 0; mt < 2; ++mt)
        #pragma unroll
        for (int jt = 0; jt < 2; ++jt) {
            float sb = sb1[jt * 16 + l16];
            int rw = (mt * 16 + quad * 4) * SST + jt * 16 + l16;
            strip[rw]           = f2b(fmaxf(hacc[mt][jt][0] + sb, 0.0f));
            strip[rw + SST]     = f2b(fmaxf(hacc[mt][jt][1] + sb, 0.0f));
            strip[rw + 2 * SST] = f2b(fmaxf(hacc[mt][jt][2] + sb, 0.0f));
            strip[rw + 3 * SST] = f2b(fmaxf(hacc[mt][jt][3] + sb, 0.0f));
        }

    // ---- phase 1b: GEMM3 max-only pass ----
    s16x8 H0 = *(const s16x8*)&strip[l16 * SST + quad * 8];
    s16x8 H1 = *(const s16x8*)&strip[(16 + l16) * SST + quad * 8];
    float mloc[16];
    #pragma unroll
    for (int ct = 0; ct < 16; ++ct) {
        f32x4 a0 = (f32x4){0.f, 0.f, 0.f, 0.f};
        f32x4 a1 = (f32x4){0.f, 0.f, 0.f, 0.f};
        s16x8 B = *(const s16x8*)(ws2 + ((size_t)ct * 64 + lane) * 8);
        a0 = __builtin_amdgcn_mfma_f32_16x16x32_bf16(H0, B, a0, 0, 0, 0);
        a1 = __builtin_amdgcn_mfma_f32_16x16x32_bf16(H1, B, a1, 0, 0, 0);
        float sb2c = sb2[ct * 16 + l16];
        float ml = -3.0e38f;
        #pragma unroll
        for (int r = 0; r < 4; ++r) {
            float s0 = vm[0][r] ? (a0[r] + sb2c) : -1e9f;
            float s1 = vm[1][r] ? (a1[r] + sb2c) : -1e9f;
            ml = fmaxf(ml, fmaxf(s0, s1));
        }
        ml = fmaxf(ml, __shfl_xor(ml, 16));
        ml = fmaxf(ml, __shfl_xor(ml, 32));
        mloc[ct] = ml;   // wave max, l16-indexed channel
    }
    __syncthreads();     // qm (poolA) dead everywhere; reuse poolA for max combine
    #pragma unroll 1
    for (int w = 0; w < 4; ++w) {
        if (wvid == w && lane < 16) {
            #pragma unroll
            for (int ct = 0; ct < 16; ++ct) {
                int x = ct * 16 + lane;
                poolA[x] = (w == 0) ? mloc[ct] : fmaxf(poolA[x], mloc[ct]);
            }
        }
        __syncthreads();
    }
    float Mf[16];
    #pragma unroll
    for (int ct = 0; ct < 16; ++ct) Mf[ct] = poolA[ct * 16 + l16];

    // ---- phase 2: recompute scores chunk-wise + V-proj chunk + fused aggregation ----
    float lsp[16], aggp[16];
    #pragma unroll
    for (int ct = 0; ct < 16; ++ct) { lsp[ct] = 0.0f; aggp[ct] = 0.0f; }

    #pragma unroll 1
    for (int ck = 0; ck < 8; ++ck) {
        float ev[2][2][4];   // [ctl][mt][r]
        #pragma unroll
        for (int ctl = 0; ctl < 2; ++ctl) {
            int ct = ck * 2 + ctl;
            f32x4 a0 = (f32x4){0.f, 0.f, 0.f, 0.f};
            f32x4 a1 = (f32x4){0.f, 0.f, 0.f, 0.f};
            s16x8 B = *(const s16x8*)(ws2 + ((size_t)ct * 64 + lane) * 8);
            a0 = __builtin_amdgcn_mfma_f32_16x16x32_bf16(H0, B, a0, 0, 0, 0);
            a1 = __builtin_amdgcn_mfma_f32_16x16x32_bf16(H1, B, a1, 0, 0, 0);
            float sb2c = sb2[ct * 16 + l16];
            float M = Mf[ct];
            float ls = 0.0f;
            #pragma unroll
            for (int r = 0; r < 4; ++r) {
                float s0 = vm[0][r] ? (a0[r] + sb2c) : -1e9f;
                float s1 = vm[1][r] ? (a1[r] + sb2c) : -1e9f;
                float e0 = __expf(s0 - M);
                float e1 = __expf(s1 - M);
                ev[ctl][0][r] = e0;
                ev[ctl][1][r] = e1;
                ls += e0 + e1;
            }
            lsp[ct] = ls;
        }
        f32x4 acc[2][2];
        #pragma unroll
        for (int mt = 0; mt < 2; ++mt)
            #pragma unroll
            for (int ctl = 0; ctl < 2; ++ctl) acc[mt][ctl] = (f32x4){0.f, 0.f, 0.f, 0.f};
        #pragma unroll
        for (int kt = 0; kt < 8; ++kt) {
            s16x8 A0 = *(const s16x8*)&keyb[aoff0 + kt * 32 + quad * 8];
            s16x8 A1 = *(const s16x8*)&keyb[aoff1 + kt * 32 + quad * 8];
            #pragma unroll
            for (int ctl = 0; ctl < 2; ++ctl) {
                s16x8 B = *(const s16x8*)(wsv + ((size_t)((ck * 2 + ctl) * 9 + kt) * 512) + lane * 8);
                acc[0][ctl] = __builtin_amdgcn_mfma_f32_16x16x32_bf16(A0, B, acc[0][ctl], 0, 0, 0);
                acc[1][ctl] = __builtin_amdgcn_mfma_f32_16x16x32_bf16(A1, B, acc[1][ctl], 0, 0, 0);
            }
        }
        #pragma unroll
        for (int ctl = 0; ctl < 2; ++ctl) {
            s16x8 B = *(const s16x8*)(wsv + ((size_t)((ck * 2 + ctl) * 9 + 8) * 512) + lane * 8);
            acc[0][ctl] = __builtin_amdgcn_mfma_f32_16x16x32_bf16(phf0.v, B, acc[0][ctl], 0, 0, 0);
            acc[1][ctl] = __builtin_amdgcn_mfma_f32_16x16x32_bf16(phf1.v, B, acc[1][ctl], 0, 0, 0);
        }
        #pragma unroll
        for (int ctl = 0; ctl < 2; ++ctl) {
            const int ct = ck * 2 + ctl;
            float pb = poolB[ct * 16 + l16];
            float a = aggp[ct];
            #pragma unroll
            for (int mt = 0; mt < 2; ++mt)
                #pragma unroll
                for (int r = 0; r < 4; ++r)
                    a = fmaf(ev[ctl][mt][r], acc[mt][ctl][r] + pb, a);
            aggp[ct] = a;
        }
    }

    // ---- reduce l and agg across lanes/waves (keys now dead -> overlay) ----
    __syncthreads();
    #pragma unroll
    for (int ct = 0; ct < 16; ++ct) {
        float a = aggp[ct];
        a += __shfl_xor(a, 16);
        a += __shfl_xor(a, 32);
        float l = lsp[ct];
        l += __shfl_xor(l, 16);
        l += __shfl_xor(l, 32);
        if (lane < 16) {
            aggpool[wvid * 256 + ct * 16 + lane] = a;
            lpool[wvid * 256 + ct * 16 + lane] = l;
        }
    }
    __syncthreads();
    {
        float asum = aggpool[t] + aggpool[256 + t] + aggpool[512 + t] + aggpool[768 + t];
        float lsum = lpool[t] + lpool[256 + t] + lpool[512 + t] + lpool[768 + t];
        poolA[t] = asum / lsum;
    }
    __syncthreads();

    // ---- epilogue 1: xres = agg@Wo + bo + query ----
    const unsigned short* wob = ws16 + WOB_OFF;
    float ao = bo[t];
    for (int k4 = 0; k4 < CC / 4; ++k4) {
        float4 a4 = *(const float4*)&poolA[k4 * 4];
        const unsigned short* w = wob + (size_t)(k4 * 4) * CC + t;
        ao = fmaf(a4.x, b2f(w[0]), ao);
        ao = fmaf(a4.y, b2f(w[CC]), ao);
        ao = fmaf(a4.z, b2f(w[2 * CC]), ao);
        ao = fmaf(a4.w, b2f(w[3 * CC]), ao);
    }
    const float xrs = ao + xq;

    // ---- epilogue 2: LN2 + FF + residual ----
    float mean2 = block_sum_256(xrs, red) * (1.0f / CC);
    float d2 = xrs - mean2;
    float var2 = block_sum_256(d2 * d2, red) * (1.0f / CC);
    float yn = d2 * rsqrtf(var2 + EPSL) * ln2g[t] + ln2b[t];
    poolA[t] = yn;
    __syncthreads();

    const unsigned short* fw1b = ws16 + FW1B_OFF;
    const unsigned short* fw2b = ws16 + FW2B_OFF;
    #pragma unroll
    for (int rr = 0; rr < 4; ++rr) {
        const int hh = t + 256 * rr;
        float hv = fb1[hh];
        for (int k4 = 0; k4 < CC / 4; ++k4) {
            float4 xv = *(const float4*)&poolA[k4 * 4];
            const unsigned short* w = fw1b + (size_t)(k4 * 4) * HIDN + hh;
            hv = fmaf(xv.x, b2f(w[0]), hv);
            hv = fmaf(xv.y, b2f(w[HIDN]), hv);
            hv = fmaf(xv.z, b2f(w[2 * HIDN]), hv);
            hv = fmaf(xv.w, b2f(w[3 * HIDN]), hv);
        }
        ffh[hh] = fmaxf(hv, 0.0f);
    }
    __syncthreads();

    float o = xrs + fb2[t];
    for (int h4 = 0; h4 < HIDN / 4; ++h4) {
        float4 hv4 = *(const float4*)&ffh[h4 * 4];
        const unsigned short* w = fw2b + (size_t)(h4 * 4) * CC + t;
        o = fmaf(hv4.x, b2f(w[0]), o);
        o = fmaf(hv4.y, b2f(w[CC]), o);
        o = fmaf(hv4.z, b2f(w[2 * CC]), o);
        o = fmaf(hv4.w, b2f(w[3 * CC]), o);
    }
    out[(size_t)bh * CC + t] = o;
}

extern "C" void kernel_launch(void* const* d_in, const int* in_sizes, int n_in,
                              void* d_out, int out_size, void* d_ws, size_t ws_size,
                              hipStream_t stream) {
    const float* qin  = (const float*)d_in[0];
    const float* kin  = (const float*)d_in[1];
    const float* rel  = (const float*)d_in[2];
    const int*   vis  = (const int*)  d_in[3];
    const float* ln1g = (const float*)d_in[4];
    const float* ln1b = (const float*)d_in[5];
    const float* ln2g = (const float*)d_in[6];
    const float* ln2b = (const float*)d_in[7];
    const float* Wq   = (const float*)d_in[8];
    const float* Wk   = (const float*)d_in[9];
    const float* Wv   = (const float*)d_in[10];
    const float* pw1  = (const float*)d_in[11];
    const float* pb1  = (const float*)d_in[12];
    const float* pw2  = (const float*)d_in[13];
    const float* pb2  = (const float*)d_in[14];
    const float* sw1  = (const float*)d_in[15];
    const float* sb1  = (const float*)d_in[16];
    const float* sw2  = (const float*)d_in[17];
    const float* sb2  = (const float*)d_in[18];
    const float* Wo   = (const float*)d_in[19];
    const float* bo   = (const float*)d_in[20];
    const float* fw1  = (const float*)d_in[21];
    const float* fb1  = (const float*)d_in[22];
    const float* fw2  = (const float*)d_in[23];
    const float* fb2  = (const float*)d_in[24];
    (void)in_sizes; (void)n_in; (void)out_size; (void)ws_size;

    unsigned short* ws16 = (unsigned short*)d_ws;
    float* o = (float*)d_out;

    prep_frags<<<dim3((NPREP + 255) / 256), dim3(256), 0, stream>>>(
        Wk, Wv, pw2, sw1, sw2, fw1, fw2, Wo, ws16);
    cft_attn<<<dim3(1024), dim3(256), 0, stream>>>(
        qin, kin, rel, vis, ln1g, ln1b, ln2g, ln2b, Wq, pw1, pb1, pb2,
        sb1, sb2, bo, fb1, fb2, ws16, o);
}

// Round 5
// 390.354 us; speedup vs baseline: 4.5564x; 1.1405x over previous
//
#include <hip/hip_runtime.h>
#include <math.h>

#define NN 128
#define CC 256
#define HIDN 1024
#define KST 264           // key slab row stride (bf16 elems)
#define SST 40            // per-wave strip row stride (bf16 elems)
#define EPSL 1e-6f

typedef short s16x8 __attribute__((ext_vector_type(8)));
typedef float f32x4 __attribute__((ext_vector_type(4)));

// ---- workspace layout ----
// bf16 units: wv blob [ct16][kt9][64][8]; wt blob (Wk@sw1 | pw2@sw1) [jt2][kt9][64][8];
// sw2 blob [ct16][64][8]; Wo bf16; fw1 bf16; fw2 bf16. Then f32: qt[1024][32], agg[1024][256].
#define WVOFF    0
#define WTOFF    73728
#define SW2OFF   82944
#define WOB_OFF  91136
#define FW1B_OFF 156672
#define FW2B_OFF 418816
#define QT_BYTE_OFF  1361920
#define AGG_BYTE_OFF 1492992

__device__ __forceinline__ unsigned short f2b(float x) {
    unsigned u = __builtin_bit_cast(unsigned, x);
    u += 0x7fffu + ((u >> 16) & 1u);
    return (unsigned short)(u >> 16);
}
__device__ __forceinline__ float b2f(unsigned short s) {
    return __builtin_bit_cast(float, ((unsigned)s) << 16);
}
__device__ __forceinline__ unsigned pack2(float a, float b) {
    return (unsigned)f2b(a) | ((unsigned)f2b(b) << 16);
}

__device__ __forceinline__ float block_sum_256(float v, float* red) {
    #pragma unroll
    for (int off = 32; off > 0; off >>= 1)
        v += __shfl_down(v, off, 64);
    const int wid = threadIdx.x >> 6;
    if ((threadIdx.x & 63) == 0) red[wid] = v;
    __syncthreads();
    float s = red[0] + red[1] + red[2] + red[3];
    __syncthreads();
    return s;
}

// ---------------- prep1: Wv/sw2 frag blobs + linear bf16 copies, 16B stores ----------------
__global__ __launch_bounds__(256)
void prep1(const float* __restrict__ Wv, const float* __restrict__ pw2,
           const float* __restrict__ sw2, const float* __restrict__ fw1,
           const float* __restrict__ fw2, const float* __restrict__ Wo,
           unsigned short* __restrict__ ws16)
{
    int e = blockIdx.x * 256 + threadIdx.x;   // 83968 total
    unsigned short v[8];
    if (e < 9216) {            // Wv blob (koct 36 x col 256)
        int koct = e >> 8, col = e & 255;
        #pragma unroll
        for (int j = 0; j < 8; ++j) {
            int k = koct * 8 + j;
            float val = (k < 256) ? Wv[k * 256 + col] : pw2[(k - 256) * 256 + col];
            v[j] = f2b(val);
        }
        int dest = WVOFF + (col >> 4) * 4608 + (koct >> 2) * 512
                 + (((((koct & 3) << 4) | (col & 15))) << 3);
        uint4 pk;
        pk.x = (unsigned)v[0] | ((unsigned)v[1] << 16);
        pk.y = (unsigned)v[2] | ((unsigned)v[3] << 16);
        pk.z = (unsigned)v[4] | ((unsigned)v[5] << 16);
        pk.w = (unsigned)v[6] | ((unsigned)v[7] << 16);
        *(uint4*)&ws16[dest] = pk;
    } else if (e < 10240) {    // sw2 blob (col 256 x koct 4)
        int i = e - 9216;
        int koct = i & 3, col = i >> 2;
        #pragma unroll
        for (int j = 0; j < 8; ++j) v[j] = f2b(sw2[(koct * 8 + j) * 256 + col]);
        int dest = SW2OFF + (col >> 4) * 512 + ((((koct << 4) | (col & 15))) << 3);
        uint4 pk;
        pk.x = (unsigned)v[0] | ((unsigned)v[1] << 16);
        pk.y = (unsigned)v[2] | ((unsigned)v[3] << 16);
        pk.z = (unsigned)v[4] | ((unsigned)v[5] << 16);
        pk.w = (unsigned)v[6] | ((unsigned)v[7] << 16);
        *(uint4*)&ws16[dest] = pk;
    } else {
        const float* src; int base, i;
        if (e < 43008)      { src = fw1; base = FW1B_OFF; i = (e - 10240) * 8; }
        else if (e < 75776) { src = fw2; base = FW2B_OFF; i = (e - 43008) * 8; }
        else                { src = Wo;  base = WOB_OFF;  i = (e - 75776) * 8; }
        float4 a = *(const float4*)(src + i);
        float4 b = *(const float4*)(src + i + 4);
        uint4 pk;
        pk.x = pack2(a.x, a.y);
        pk.y = pack2(a.z, a.w);
        pk.z = pack2(b.x, b.y);
        pk.w = pack2(b.z, b.w);
        *(uint4*)&ws16[base + i] = pk;
    }
}

// ---------------- prep2: Wt = (Wk | pw2) @ sw1, fp32 dot -> bf16 frag blob ----------------
__global__ __launch_bounds__(256)
void prep2(const float* __restrict__ Wk, const float* __restrict__ pw2,
           const float* __restrict__ sw1, unsigned short* __restrict__ ws16)
{
    int tid = blockIdx.x * 256 + threadIdx.x;   // 9216
    int k = tid >> 5, j = tid & 31;
    const float* row = (k < 256) ? (Wk + (size_t)k * 256) : (pw2 + (size_t)(k - 256) * 256);
    float s = 0.0f;
    for (int c = 0; c < 256; ++c) s = fmaf(row[c], sw1[c * 32 + j], s);
    int dest = WTOFF + ((j >> 4) * 9 + (k >> 5)) * 512
             + ((((((k >> 3) & 3) << 4) | (j & 15))) << 3) + (k & 7);
    ws16[dest] = f2b(s);
}

// ---------------- qprep: LN1 + q = xln@Wq ; qt = (pb2-q)@sw1 + sb1 ----------------
__global__ __launch_bounds__(256)
void qprep(const float* __restrict__ qin,
           const float* __restrict__ ln1g, const float* __restrict__ ln1b,
           const float* __restrict__ Wq, const float* __restrict__ pb2,
           const float* __restrict__ sw1, const float* __restrict__ sb1,
           float* __restrict__ qt)
{
    __shared__ __align__(16) float xlnL[4][CC];
    __shared__ __align__(16) float qmL[4][CC];
    const int t = threadIdx.x;
    const int lane = t & 63;
    const int r = t >> 6;
    const int b0 = blockIdx.x * 4;
    const size_t rowoff = (size_t)(b0 + r) * CC;

    float v0 = qin[rowoff + lane];
    float v1 = qin[rowoff + lane + 64];
    float v2 = qin[rowoff + lane + 128];
    float v3 = qin[rowoff + lane + 192];
    float s = v0 + v1 + v2 + v3;
    #pragma unroll
    for (int off = 32; off > 0; off >>= 1) s += __shfl_xor(s, off);
    float mean = s * (1.0f / CC);
    float d0 = v0 - mean, d1 = v1 - mean, d2 = v2 - mean, d3 = v3 - mean;
    float vs = d0 * d0 + d1 * d1 + d2 * d2 + d3 * d3;
    #pragma unroll
    for (int off = 32; off > 0; off >>= 1) vs += __shfl_xor(vs, off);
    float rstd = rsqrtf(vs * (1.0f / CC) + EPSL);
    xlnL[r][lane]       = d0 * rstd * ln1g[lane] + ln1b[lane];
    xlnL[r][lane + 64]  = d1 * rstd * ln1g[lane + 64] + ln1b[lane + 64];
    xlnL[r][lane + 128] = d2 * rstd * ln1g[lane + 128] + ln1b[lane + 128];
    xlnL[r][lane + 192] = d3 * rstd * ln1g[lane + 192] + ln1b[lane + 192];
    __syncthreads();

    float q0 = 0.f, q1 = 0.f, q2 = 0.f, q3 = 0.f;
    for (int k4 = 0; k4 < CC / 4; ++k4) {
        float4 x0 = *(const float4*)&xlnL[0][k4 * 4];
        float4 x1 = *(const float4*)&xlnL[1][k4 * 4];
        float4 x2 = *(const float4*)&xlnL[2][k4 * 4];
        float4 x3 = *(const float4*)&xlnL[3][k4 * 4];
        const float* w = Wq + (size_t)(k4 * 4) * CC + t;
        float w0 = w[0], w1 = w[CC], w2 = w[2 * CC], w3 = w[3 * CC];
        q0 = fmaf(x0.x, w0, fmaf(x0.y, w1, fmaf(x0.z, w2, fmaf(x0.w, w3, q0))));
        q1 = fmaf(x1.x, w0, fmaf(x1.y, w1, fmaf(x1.z, w2, fmaf(x1.w, w3, q1))));
        q2 = fmaf(x2.x, w0, fmaf(x2.y, w1, fmaf(x2.z, w2, fmaf(x2.w, w3, q2))));
        q3 = fmaf(x3.x, w0, fmaf(x3.y, w1, fmaf(x3.z, w2, fmaf(x3.w, w3, q3))));
    }
    float pb = pb2[t];
    qmL[0][t] = pb - q0;
    qmL[1][t] = pb - q1;
    qmL[2][t] = pb - q2;
    qmL[3][t] = pb - q3;
    __syncthreads();

    if (t < 128) {
        int r2 = t >> 5, j = t & 31;
        float acc = sb1[j];
        for (int c = 0; c < 256; ++c) acc = fmaf(qmL[r2][c], sw1[c * 32 + j], acc);
        qt[(size_t)(b0 + r2) * 32 + j] = acc;
    }
}

// ---------------- attn: per (b,h): H-GEMM + score-max + fused recompute/V/agg ----------------
__global__ __launch_bounds__(256, 2)
void cft_attn(const float* __restrict__ kin, const float* __restrict__ rel,
              const int* __restrict__ vis,
              const float* __restrict__ pw1, const float* __restrict__ pb1,
              const float* __restrict__ pb2, const float* __restrict__ sb2,
              const unsigned short* __restrict__ ws16,
              const float* __restrict__ qt,
              float* __restrict__ aggout)
{
    __shared__ __align__(16) unsigned char smem[80032];
    unsigned short* keyb = (unsigned short*)smem;              // 128 x KST bf16 = 67584 B
    float* poolA = (float*)(smem + 77824);                     // Mmax combine
    float* poolB = (float*)(smem + 78848);                     // pb2
    unsigned char* visb = smem + 79872;
    float* aggpool = (float*)smem;                             // overlay after phase2
    float* lpool   = (float*)(smem + 4096);

    const int bh = blockIdx.x;
    const int t = threadIdx.x;
    const int lane = t & 63;
    const int wvid = t >> 6;
    const int quad = lane >> 4;
    const int l16 = lane & 15;
    const int rb = wvid * 32;
    unsigned short* strip = (unsigned short*)(smem + 67584) + wvid * (32 * SST);

    // stage keys -> bf16 LDS
    const float4* kb4 = (const float4*)(kin + (size_t)bh * NN * CC);
    #pragma unroll
    for (int i = 0; i < 32; ++i) {
        int flat = i * 256 + t;
        int row = flat >> 6;
        int cu = flat & 63;
        float4 kv = kb4[flat];
        uint2 pk;
        pk.x = pack2(kv.x, kv.y);
        pk.y = pack2(kv.z, kv.w);
        *(uint2*)&keyb[row * KST + cu * 4] = pk;
    }
    if (t < NN) visb[t] = (unsigned char)(vis[(size_t)bh * NN + t] != 0);
    poolB[t] = pb2[t];

    // pos-MLP A-fragments (kt==8)
    union { s16x8 v; unsigned short u[8]; } phf0, phf1;
    {
        const int row0 = rb + l16, row1 = rb + 16 + l16;
        float4 r40 = *(const float4*)(rel + ((size_t)bh * NN + row0) * 4);
        float4 r41 = *(const float4*)(rel + ((size_t)bh * NN + row1) * 4);
        #pragma unroll
        for (int j = 0; j < 8; ++j) {
            int col = quad * 8 + j;
            float w0 = pw1[col], w1 = pw1[32 + col], w2 = pw1[64 + col], w3 = pw1[96 + col];
            float b = pb1[col];
            float v0 = fmaf(r40.x, w0, fmaf(r40.y, w1, fmaf(r40.z, w2, fmaf(r40.w, w3, b))));
            float v1 = fmaf(r41.x, w0, fmaf(r41.y, w1, fmaf(r41.z, w2, fmaf(r41.w, w3, b))));
            phf0.u[j] = f2b(fmaxf(v0, 0.0f));
            phf1.u[j] = f2b(fmaxf(v1, 0.0f));
        }
    }
    const float qt0 = qt[(size_t)bh * 32 + l16];
    const float qt1 = qt[(size_t)bh * 32 + 16 + l16];
    __syncthreads();

    const int aoff0 = (rb + l16) * KST;
    const int aoff1 = (rb + 16 + l16) * KST;
    const unsigned short* wsv = ws16 + WVOFF;
    const unsigned short* wst = ws16 + WTOFF;
    const unsigned short* ws2 = ws16 + SW2OFF;

    unsigned char vm[2][4];
    #pragma unroll
    for (int mt = 0; mt < 2; ++mt)
        #pragma unroll
        for (int r = 0; r < 4; ++r) vm[mt][r] = visb[rb + mt * 16 + quad * 4 + r];

    // ---- phase 1: H-GEMM  h1pre = Kin@Wt + ph@Wtpos + qt ----
    f32x4 hacc[2][2];
    #pragma unroll
    for (int mt = 0; mt < 2; ++mt)
        #pragma unroll
        for (int jt = 0; jt < 2; ++jt) hacc[mt][jt] = (f32x4){0.f, 0.f, 0.f, 0.f};
    #pragma unroll
    for (int kt = 0; kt < 8; ++kt) {
        s16x8 A0 = *(const s16x8*)&keyb[aoff0 + kt * 32 + quad * 8];
        s16x8 A1 = *(const s16x8*)&keyb[aoff1 + kt * 32 + quad * 8];
        #pragma unroll
        for (int jt = 0; jt < 2; ++jt) {
            s16x8 B = *(const s16x8*)(wst + (size_t)(jt * 9 + kt) * 512 + lane * 8);
            hacc[0][jt] = __builtin_amdgcn_mfma_f32_16x16x32_bf16(A0, B, hacc[0][jt], 0, 0, 0);
            hacc[1][jt] = __builtin_amdgcn_mfma_f32_16x16x32_bf16(A1, B, hacc[1][jt], 0, 0, 0);
        }
    }
    #pragma unroll
    for (int jt = 0; jt < 2; ++jt) {   // kt == 8: pos fragment
        s16x8 B = *(const s16x8*)(wst + (size_t)(jt * 9 + 8) * 512 + lane * 8);
        hacc[0][jt] = __builtin_amdgcn_mfma_f32_16x16x32_bf16(phf0.v, B, hacc[0][jt], 0, 0, 0);
        hacc[1][jt] = __builtin_amdgcn_mfma_f32_16x16x32_bf16(phf1.v, B, hacc[1][jt], 0, 0, 0);
    }
    // h1 = relu(hacc + qt) -> strip
    #pragma unroll
    for (int mt = 0; mt < 2; ++mt)
        #pragma unroll
        for (int jt = 0; jt < 2; ++jt) {
            float qv = jt ? qt1 : qt0;
            int rw = (mt * 16 + quad * 4) * SST + jt * 16 + l16;
            strip[rw]           = f2b(fmaxf(hacc[mt][jt][0] + qv, 0.0f));
            strip[rw + SST]     = f2b(fmaxf(hacc[mt][jt][1] + qv, 0.0f));
            strip[rw + 2 * SST] = f2b(fmaxf(hacc[mt][jt][2] + qv, 0.0f));
            strip[rw + 3 * SST] = f2b(fmaxf(hacc[mt][jt][3] + qv, 0.0f));
        }

    // ---- phase 1b: score max pass ----
    s16x8 H0 = *(const s16x8*)&strip[l16 * SST + quad * 8];
    s16x8 H1 = *(const s16x8*)&strip[(16 + l16) * SST + quad * 8];
    float mloc[16];
    #pragma unroll
    for (int ct = 0; ct < 16; ++ct) {
        f32x4 a0 = (f32x4){0.f, 0.f, 0.f, 0.f};
        f32x4 a1 = (f32x4){0.f, 0.f, 0.f, 0.f};
        s16x8 B = *(const s16x8*)(ws2 + ((size_t)ct * 64 + lane) * 8);
        a0 = __builtin_amdgcn_mfma_f32_16x16x32_bf16(H0, B, a0, 0, 0, 0);
        a1 = __builtin_amdgcn_mfma_f32_16x16x32_bf16(H1, B, a1, 0, 0, 0);
        float sb2c = sb2[ct * 16 + l16];
        float ml = -3.0e38f;
        #pragma unroll
        for (int r = 0; r < 4; ++r) {
            float s0 = vm[0][r] ? (a0[r] + sb2c) : -1e9f;
            float s1 = vm[1][r] ? (a1[r] + sb2c) : -1e9f;
            ml = fmaxf(ml, fmaxf(s0, s1));
        }
        ml = fmaxf(ml, __shfl_xor(ml, 16));
        ml = fmaxf(ml, __shfl_xor(ml, 32));
        mloc[ct] = ml;
    }
    __syncthreads();
    #pragma unroll 1
    for (int w = 0; w < 4; ++w) {
        if (wvid == w && lane < 16) {
            #pragma unroll
            for (int ct = 0; ct < 16; ++ct) {
                int x = ct * 16 + lane;
                poolA[x] = (w == 0) ? mloc[ct] : fmaxf(poolA[x], mloc[ct]);
            }
        }
        __syncthreads();
    }
    float Mf[16];
    #pragma unroll
    for (int ct = 0; ct < 16; ++ct) Mf[ct] = poolA[ct * 16 + l16];

    // ---- phase 2: score recompute + V chunk + fused aggregation ----
    float lsp[16], aggp[16];
    #pragma unroll
    for (int ct = 0; ct < 16; ++ct) { lsp[ct] = 0.0f; aggp[ct] = 0.0f; }

    #pragma unroll 1
    for (int ck = 0; ck < 8; ++ck) {
        float ev[2][2][4];   // [ctl][mt][r]
        #pragma unroll
        for (int ctl = 0; ctl < 2; ++ctl) {
            int ct = ck * 2 + ctl;
            f32x4 a0 = (f32x4){0.f, 0.f, 0.f, 0.f};
            f32x4 a1 = (f32x4){0.f, 0.f, 0.f, 0.f};
            s16x8 B = *(const s16x8*)(ws2 + ((size_t)ct * 64 + lane) * 8);
            a0 = __builtin_amdgcn_mfma_f32_16x16x32_bf16(H0, B, a0, 0, 0, 0);
            a1 = __builtin_amdgcn_mfma_f32_16x16x32_bf16(H1, B, a1, 0, 0, 0);
            float sb2c = sb2[ct * 16 + l16];
            float M = Mf[ct];
            float ls = 0.0f;
            #pragma unroll
            for (int r = 0; r < 4; ++r) {
                float s0 = vm[0][r] ? (a0[r] + sb2c) : -1e9f;
                float s1 = vm[1][r] ? (a1[r] + sb2c) : -1e9f;
                float e0 = __expf(s0 - M);
                float e1 = __expf(s1 - M);
                ev[ctl][0][r] = e0;
                ev[ctl][1][r] = e1;
                ls += e0 + e1;
            }
            lsp[ct] = ls;
        }
        f32x4 acc[2][2];
        #pragma unroll
        for (int mt = 0; mt < 2; ++mt)
            #pragma unroll
            for (int ctl = 0; ctl < 2; ++ctl) acc[mt][ctl] = (f32x4){0.f, 0.f, 0.f, 0.f};
        #pragma unroll
        for (int kt = 0; kt < 8; ++kt) {
            s16x8 A0 = *(const s16x8*)&keyb[aoff0 + kt * 32 + quad * 8];
            s16x8 A1 = *(const s16x8*)&keyb[aoff1 + kt * 32 + quad * 8];
            #pragma unroll
            for (int ctl = 0; ctl < 2; ++ctl) {
                s16x8 B = *(const s16x8*)(wsv + ((size_t)((ck * 2 + ctl) * 9 + kt) * 512) + lane * 8);
                acc[0][ctl] = __builtin_amdgcn_mfma_f32_16x16x32_bf16(A0, B, acc[0][ctl], 0, 0, 0);
                acc[1][ctl] = __builtin_amdgcn_mfma_f32_16x16x32_bf16(A1, B, acc[1][ctl], 0, 0, 0);
            }
        }
        #pragma unroll
        for (int ctl = 0; ctl < 2; ++ctl) {
            s16x8 B = *(const s16x8*)(wsv + ((size_t)((ck * 2 + ctl) * 9 + 8) * 512) + lane * 8);
            acc[0][ctl] = __builtin_amdgcn_mfma_f32_16x16x32_bf16(phf0.v, B, acc[0][ctl], 0, 0, 0);
            acc[1][ctl] = __builtin_amdgcn_mfma_f32_16x16x32_bf16(phf1.v, B, acc[1][ctl], 0, 0, 0);
        }
        #pragma unroll
        for (int ctl = 0; ctl < 2; ++ctl) {
            const int ct = ck * 2 + ctl;
            float pb = poolB[ct * 16 + l16];
            float a = aggp[ct];
            #pragma unroll
            for (int mt = 0; mt < 2; ++mt)
                #pragma unroll
                for (int r = 0; r < 4; ++r)
                    a = fmaf(ev[ctl][mt][r], acc[mt][ctl][r] + pb, a);
            aggp[ct] = a;
        }
    }

    // ---- reduce l and agg across lanes/waves; write agg row ----
    __syncthreads();
    #pragma unroll
    for (int ct = 0; ct < 16; ++ct) {
        float a = aggp[ct];
        a += __shfl_xor(a, 16);
        a += __shfl_xor(a, 32);
        float l = lsp[ct];
        l += __shfl_xor(l, 16);
        l += __shfl_xor(l, 32);
        if (lane < 16) {
            aggpool[wvid * 256 + ct * 16 + lane] = a;
            lpool[wvid * 256 + ct * 16 + lane] = l;
        }
    }
    __syncthreads();
    {
        float asum = aggpool[t] + aggpool[256 + t] + aggpool[512 + t] + aggpool[768 + t];
        float lsum = lpool[t] + lpool[256 + t] + lpool[512 + t] + lpool[768 + t];
        aggout[(size_t)bh * CC + t] = asum / lsum;
    }
}

// ---------------- ffo: xres = agg@Wo + bo + qin; LN2; FF; out  (4 rows/block) ----------------
__global__ __launch_bounds__(256, 2)
void cft_ffo(const float* __restrict__ aggp, const float* __restrict__ qin,
             const float* __restrict__ bo,
             const float* __restrict__ ln2g, const float* __restrict__ ln2b,
             const unsigned short* __restrict__ ws16,
             const float* __restrict__ fb1, const float* __restrict__ fb2,
             float* __restrict__ out)
{
    __shared__ __align__(16) float aggL[4][CC];
    __shared__ __align__(16) float xlnL[4][CC];
    __shared__ __align__(16) float ffh[4][HIDN];
    __shared__ float red[4];
    const int t = threadIdx.x;
    const int b0 = blockIdx.x * 4;
    const unsigned short* wob  = ws16 + WOB_OFF;
    const unsigned short* fw1b = ws16 + FW1B_OFF;
    const unsigned short* fw2b = ws16 + FW2B_OFF;

    float xq[4];
    #pragma unroll
    for (int i = 0; i < 4; ++i) {
        aggL[i][t] = aggp[(size_t)(b0 + i) * CC + t];
        xq[i] = qin[(size_t)(b0 + i) * CC + t];
    }
    __syncthreads();

    float ao[4];
    {
        float b = bo[t];
        #pragma unroll
        for (int i = 0; i < 4; ++i) ao[i] = b;
    }
    for (int k4 = 0; k4 < CC / 4; ++k4) {
        float4 a0 = *(const float4*)&aggL[0][k4 * 4];
        float4 a1 = *(const float4*)&aggL[1][k4 * 4];
        float4 a2 = *(const float4*)&aggL[2][k4 * 4];
        float4 a3 = *(const float4*)&aggL[3][k4 * 4];
        const unsigned short* w = wob + (size_t)(k4 * 4) * CC + t;
        float w0 = b2f(w[0]), w1 = b2f(w[CC]), w2 = b2f(w[2 * CC]), w3 = b2f(w[3 * CC]);
        ao[0] = fmaf(a0.x, w0, fmaf(a0.y, w1, fmaf(a0.z, w2, fmaf(a0.w, w3, ao[0]))));
        ao[1] = fmaf(a1.x, w0, fmaf(a1.y, w1, fmaf(a1.z, w2, fmaf(a1.w, w3, ao[1]))));
        ao[2] = fmaf(a2.x, w0, fmaf(a2.y, w1, fmaf(a2.z, w2, fmaf(a2.w, w3, ao[2]))));
        ao[3] = fmaf(a3.x, w0, fmaf(a3.y, w1, fmaf(a3.z, w2, fmaf(a3.w, w3, ao[3]))));
    }
    float xrs[4];
    #pragma unroll
    for (int i = 0; i < 4; ++i) xrs[i] = ao[i] + xq[i];
    __syncthreads();

    #pragma unroll
    for (int row = 0; row < 4; ++row) {
        float x = xrs[row];
        float mean = block_sum_256(x, red) * (1.0f / CC);
        float d = x - mean;
        float var = block_sum_256(d * d, red) * (1.0f / CC);
        xlnL[row][t] = d * rsqrtf(var + EPSL) * ln2g[t] + ln2b[t];
    }
    __syncthreads();
    {
        float acc[4][4];
        #pragma unroll
        for (int rr = 0; rr < 4; ++rr) {
            float b = fb1[t + 256 * rr];
            #pragma unroll
            for (int row = 0; row < 4; ++row) acc[rr][row] = b;
        }
        for (int k4 = 0; k4 < CC / 4; ++k4) {
            float4 xv[4];
            #pragma unroll
            for (int row = 0; row < 4; ++row) xv[row] = *(const float4*)&xlnL[row][k4 * 4];
            #pragma unroll
            for (int rr = 0; rr < 4; ++rr) {
                const unsigned short* w = fw1b + (size_t)(k4 * 4) * HIDN + t + 256 * rr;
                float w0 = b2f(w[0]), w1 = b2f(w[HIDN]), w2 = b2f(w[2 * HIDN]), w3 = b2f(w[3 * HIDN]);
                #pragma unroll
                for (int row = 0; row < 4; ++row)
                    acc[rr][row] = fmaf(xv[row].x, w0, fmaf(xv[row].y, w1,
                                   fmaf(xv[row].z, w2, fmaf(xv[row].w, w3, acc[rr][row]))));
            }
        }
        #pragma unroll
        for (int rr = 0; rr < 4; ++rr)
            #pragma unroll
            for (int row = 0; row < 4; ++row)
                ffh[row][t + 256 * rr] = fmaxf(acc[rr][row], 0.0f);
    }
    __syncthreads();
    {
        float o[4];
        #pragma unroll
        for (int row = 0; row < 4; ++row) o[row] = xrs[row] + fb2[t];
        for (int h4 = 0; h4 < HIDN / 4; ++h4) {
            const unsigned short* w = fw2b + (size_t)(h4 * 4) * CC + t;
            float w0 = b2f(w[0]), w1 = b2f(w[CC]), w2 = b2f(w[2 * CC]), w3 = b2f(w[3 * CC]);
            #pragma unroll
            for (int row = 0; row < 4; ++row) {
                float4 hv = *(const float4*)&ffh[row][h4 * 4];
                o[row] = fmaf(hv.x, w0, fmaf(hv.y, w1, fmaf(hv.z, w2, fmaf(hv.w, w3, o[row]))));
            }
        }
        #pragma unroll
        for (int row = 0; row < 4; ++row) out[(size_t)(b0 + row) * CC + t] = o[row];
    }
}

extern "C" void kernel_launch(void* const* d_in, const int* in_sizes, int n_in,
                              void* d_out, int out_size, void* d_ws, size_t ws_size,
                              hipStream_t stream) {
    const float* qin  = (const float*)d_in[0];
    const float* kin  = (const float*)d_in[1];
    const float* rel  = (const float*)d_in[2];
    const int*   vis  = (const int*)  d_in[3];
    const float* ln1g = (const float*)d_in[4];
    const float* ln1b = (const float*)d_in[5];
    const float* ln2g = (const float*)d_in[6];
    const float* ln2b = (const float*)d_in[7];
    const float* Wq   = (const float*)d_in[8];
    const float* Wk   = (const float*)d_in[9];
    const float* Wv   = (const float*)d_in[10];
    const float* pw1  = (const float*)d_in[11];
    const float* pb1  = (const float*)d_in[12];
    const float* pw2  = (const float*)d_in[13];
    const float* pb2  = (const float*)d_in[14];
    const float* sw1  = (const float*)d_in[15];
    const float* sb1  = (const float*)d_in[16];
    const float* sw2  = (const float*)d_in[17];
    const float* sb2  = (const float*)d_in[18];
    const float* Wo   = (const float*)d_in[19];
    const float* bo   = (const float*)d_in[20];
    const float* fw1  = (const float*)d_in[21];
    const float* fb1  = (const float*)d_in[22];
    const float* fw2  = (const float*)d_in[23];
    const float* fb2  = (const float*)d_in[24];
    (void)in_sizes; (void)n_in; (void)out_size; (void)ws_size;

    unsigned short* ws16 = (unsigned short*)d_ws;
    float* qt   = (float*)((char*)d_ws + QT_BYTE_OFF);
    float* aggb = (float*)((char*)d_ws + AGG_BYTE_OFF);
    float* o = (float*)d_out;

    prep1<<<dim3(328), dim3(256), 0, stream>>>(Wv, pw2, sw2, fw1, fw2, Wo, ws16);
    prep2<<<dim3(36), dim3(256), 0, stream>>>(Wk, pw2, sw1, ws16);
    qprep<<<dim3(256), dim3(256), 0, stream>>>(qin, ln1g, ln1b, Wq, pb2, sw1, sb1, qt);
    cft_attn<<<dim3(1024), dim3(256), 0, stream>>>(
        kin, rel, vis, pw1, pb1, pb2, sb2, ws16, qt, aggb);
    cft_ffo<<<dim3(256), dim3(256), 0, stream>>>(
        aggb, qin, bo, ln2g, ln2b, ws16, fb1, fb2, o);
}

// Round 6
// 352.405 us; speedup vs baseline: 5.0471x; 1.1077x over previous
//
#include <hip/hip_runtime.h>
#include <math.h>

#define NN 128
#define CC 256
#define HIDN 1024
#define KST 264           // key slab row stride (bf16 elems)
#define SST 40            // per-wave strip row stride (bf16 elems)
#define EPSL 1e-6f

typedef short s16x8 __attribute__((ext_vector_type(8)));
typedef float f32x4 __attribute__((ext_vector_type(4)));

// ---- workspace layout ----
// bf16 units: wv blob [ct16][kt9][64][8]; wt blob [jt2][kt9][64][8]; sw2 blob [ct16][64][8];
// Wo bf16; fw1 bf16; fw2 bf16. f32: qt[1024][32], agg[1024][256], Wqt[256][32], qtc[32].
#define WVOFF    0
#define WTOFF    73728
#define SW2OFF   82944
#define WOB_OFF  91136
#define FW1B_OFF 156672
#define FW2B_OFF 418816
#define QT_BYTE_OFF   1361920
#define AGG_BYTE_OFF  1492992
#define WQT_BYTE_OFF  2541568
#define QTC_BYTE_OFF  2574336

__device__ __forceinline__ unsigned short f2b(float x) {
    unsigned u = __builtin_bit_cast(unsigned, x);
    u += 0x7fffu + ((u >> 16) & 1u);
    return (unsigned short)(u >> 16);
}
__device__ __forceinline__ float b2f(unsigned short s) {
    return __builtin_bit_cast(float, ((unsigned)s) << 16);
}
__device__ __forceinline__ float blo(unsigned u) { return b2f((unsigned short)u); }
__device__ __forceinline__ float bhi(unsigned u) { return b2f((unsigned short)(u >> 16)); }
__device__ __forceinline__ unsigned pack2(float a, float b) {
    return (unsigned)f2b(a) | ((unsigned)f2b(b) << 16);
}

__device__ __forceinline__ float block_sum_256(float v, float* red) {
    #pragma unroll
    for (int off = 32; off > 0; off >>= 1)
        v += __shfl_down(v, off, 64);
    const int wid = threadIdx.x >> 6;
    if ((threadIdx.x & 63) == 0) red[wid] = v;
    __syncthreads();
    float s = red[0] + red[1] + red[2] + red[3];
    __syncthreads();
    return s;
}

// ---------------- prep (merged): blobs + Wt + Wqt + qtc ----------------
__global__ __launch_bounds__(256)
void prep_all(const float* __restrict__ Wk, const float* __restrict__ Wv,
              const float* __restrict__ Wq,
              const float* __restrict__ pw2, const float* __restrict__ sw1,
              const float* __restrict__ sw2, const float* __restrict__ fw1,
              const float* __restrict__ fw2, const float* __restrict__ Wo,
              const float* __restrict__ pb2, const float* __restrict__ sb1,
              unsigned short* __restrict__ ws16,
              float* __restrict__ wqt, float* __restrict__ qtc)
{
    int e = blockIdx.x * 256 + threadIdx.x;   // 101632 total
    unsigned short v[8];
    if (e < 9216) {            // Wv blob (koct 36 x col 256)
        int koct = e >> 8, col = e & 255;
        #pragma unroll
        for (int j = 0; j < 8; ++j) {
            int k = koct * 8 + j;
            float val = (k < 256) ? Wv[k * 256 + col] : pw2[(k - 256) * 256 + col];
            v[j] = f2b(val);
        }
        int dest = WVOFF + (col >> 4) * 4608 + (koct >> 2) * 512
                 + (((((koct & 3) << 4) | (col & 15))) << 3);
        uint4 pk;
        pk.x = (unsigned)v[0] | ((unsigned)v[1] << 16);
        pk.y = (unsigned)v[2] | ((unsigned)v[3] << 16);
        pk.z = (unsigned)v[4] | ((unsigned)v[5] << 16);
        pk.w = (unsigned)v[6] | ((unsigned)v[7] << 16);
        *(uint4*)&ws16[dest] = pk;
    } else if (e < 10240) {    // sw2 blob
        int i = e - 9216;
        int koct = i & 3, col = i >> 2;
        #pragma unroll
        for (int j = 0; j < 8; ++j) v[j] = f2b(sw2[(koct * 8 + j) * 256 + col]);
        int dest = SW2OFF + (col >> 4) * 512 + ((((koct << 4) | (col & 15))) << 3);
        uint4 pk;
        pk.x = (unsigned)v[0] | ((unsigned)v[1] << 16);
        pk.y = (unsigned)v[2] | ((unsigned)v[3] << 16);
        pk.z = (unsigned)v[4] | ((unsigned)v[5] << 16);
        pk.w = (unsigned)v[6] | ((unsigned)v[7] << 16);
        *(uint4*)&ws16[dest] = pk;
    } else if (e < 83968) {    // linear bf16 copies
        const float* src; int base, i;
        if (e < 43008)      { src = fw1; base = FW1B_OFF; i = (e - 10240) * 8; }
        else if (e < 75776) { src = fw2; base = FW2B_OFF; i = (e - 43008) * 8; }
        else                { src = Wo;  base = WOB_OFF;  i = (e - 75776) * 8; }
        float4 a = *(const float4*)(src + i);
        float4 b = *(const float4*)(src + i + 4);
        uint4 pk;
        pk.x = pack2(a.x, a.y);
        pk.y = pack2(a.z, a.w);
        pk.z = pack2(b.x, b.y);
        pk.w = pack2(b.z, b.w);
        *(uint4*)&ws16[base + i] = pk;
    } else if (e < 93184) {    // Wt = (Wk | pw2) @ sw1
        int tid = e - 83968;
        int k = tid >> 5, j = tid & 31;
        const float* row = (k < 256) ? (Wk + (size_t)k * 256) : (pw2 + (size_t)(k - 256) * 256);
        float s = 0.0f;
        for (int c = 0; c < 256; ++c) s = fmaf(row[c], sw1[c * 32 + j], s);
        int dest = WTOFF + ((j >> 4) * 9 + (k >> 5)) * 512
                 + ((((((k >> 3) & 3) << 4) | (j & 15))) << 3) + (k & 7);
        ws16[dest] = f2b(s);
    } else if (e < 101376) {   // Wqt = Wq @ sw1 (fp32)
        int tid = e - 93184;
        int c = tid >> 5, j = tid & 31;
        const float* row = Wq + (size_t)c * 256;
        float s = 0.0f;
        for (int cp = 0; cp < 256; ++cp) s = fmaf(row[cp], sw1[cp * 32 + j], s);
        wqt[c * 32 + j] = s;
    } else {                   // qtc = pb2@sw1 + sb1
        int j = e - 101376;
        if (j < 32) {
            float s = sb1[j];
            for (int c = 0; c < 256; ++c) s = fmaf(pb2[c], sw1[c * 32 + j], s);
            qtc[j] = s;
        }
    }
}

// ---------------- qprep2: LN1 ; qt = qtc - xln@Wqt  (4 rows/block) ----------------
__global__ __launch_bounds__(256)
void qprep2(const float* __restrict__ qin,
            const float* __restrict__ ln1g, const float* __restrict__ ln1b,
            const float* __restrict__ wqt, const float* __restrict__ qtc,
            float* __restrict__ qt)
{
    __shared__ __align__(16) float xlnL[4][CC];
    const int t = threadIdx.x;
    const int lane = t & 63;
    const int r = t >> 6;
    const int b0 = blockIdx.x * 4;
    const size_t rowoff = (size_t)(b0 + r) * CC;

    float v0 = qin[rowoff + lane];
    float v1 = qin[rowoff + lane + 64];
    float v2 = qin[rowoff + lane + 128];
    float v3 = qin[rowoff + lane + 192];
    float s = v0 + v1 + v2 + v3;
    #pragma unroll
    for (int off = 32; off > 0; off >>= 1) s += __shfl_xor(s, off);
    float mean = s * (1.0f / CC);
    float d0 = v0 - mean, d1 = v1 - mean, d2 = v2 - mean, d3 = v3 - mean;
    float vs = d0 * d0 + d1 * d1 + d2 * d2 + d3 * d3;
    #pragma unroll
    for (int off = 32; off > 0; off >>= 1) vs += __shfl_xor(vs, off);
    float rstd = rsqrtf(vs * (1.0f / CC) + EPSL);
    xlnL[r][lane]       = d0 * rstd * ln1g[lane] + ln1b[lane];
    xlnL[r][lane + 64]  = d1 * rstd * ln1g[lane + 64] + ln1b[lane + 64];
    xlnL[r][lane + 128] = d2 * rstd * ln1g[lane + 128] + ln1b[lane + 128];
    xlnL[r][lane + 192] = d3 * rstd * ln1g[lane + 192] + ln1b[lane + 192];
    __syncthreads();

    if (t < 128) {
        int r2 = t >> 5, j = t & 31;
        float acc = qtc[j];
        for (int c = 0; c < 256; ++c) acc = fmaf(-xlnL[r2][c], wqt[c * 32 + j], acc);
        qt[(size_t)(b0 + r2) * 32 + j] = acc;
    }
}

// ---------------- attn: per (b,h): H-GEMM + score-max + fused recompute/V/agg ----------------
__global__ __launch_bounds__(256, 2)
void cft_attn(const float* __restrict__ kin, const float* __restrict__ rel,
              const int* __restrict__ vis,
              const float* __restrict__ pw1, const float* __restrict__ pb1,
              const float* __restrict__ pb2, const float* __restrict__ sb2,
              const unsigned short* __restrict__ ws16,
              const float* __restrict__ qt,
              float* __restrict__ aggout)
{
    __shared__ __align__(16) unsigned char smem[80032];
    unsigned short* keyb = (unsigned short*)smem;
    float* poolA = (float*)(smem + 77824);
    float* poolB = (float*)(smem + 78848);
    unsigned char* visb = smem + 79872;
    float* aggpool = (float*)smem;
    float* lpool   = (float*)(smem + 4096);

    const int bh = blockIdx.x;
    const int t = threadIdx.x;
    const int lane = t & 63;
    const int wvid = t >> 6;
    const int quad = lane >> 4;
    const int l16 = lane & 15;
    const int rb = wvid * 32;
    unsigned short* strip = (unsigned short*)(smem + 67584) + wvid * (32 * SST);

    const float4* kb4 = (const float4*)(kin + (size_t)bh * NN * CC);
    #pragma unroll
    for (int i = 0; i < 32; ++i) {
        int flat = i * 256 + t;
        int row = flat >> 6;
        int cu = flat & 63;
        float4 kv = kb4[flat];
        uint2 pk;
        pk.x = pack2(kv.x, kv.y);
        pk.y = pack2(kv.z, kv.w);
        *(uint2*)&keyb[row * KST + cu * 4] = pk;
    }
    if (t < NN) visb[t] = (unsigned char)(vis[(size_t)bh * NN + t] != 0);
    poolB[t] = pb2[t];

    union { s16x8 v; unsigned short u[8]; } phf0, phf1;
    {
        const int row0 = rb + l16, row1 = rb + 16 + l16;
        float4 r40 = *(const float4*)(rel + ((size_t)bh * NN + row0) * 4);
        float4 r41 = *(const float4*)(rel + ((size_t)bh * NN + row1) * 4);
        #pragma unroll
        for (int j = 0; j < 8; ++j) {
            int col = quad * 8 + j;
            float w0 = pw1[col], w1 = pw1[32 + col], w2 = pw1[64 + col], w3 = pw1[96 + col];
            float b = pb1[col];
            float v0 = fmaf(r40.x, w0, fmaf(r40.y, w1, fmaf(r40.z, w2, fmaf(r40.w, w3, b))));
            float v1 = fmaf(r41.x, w0, fmaf(r41.y, w1, fmaf(r41.z, w2, fmaf(r41.w, w3, b))));
            phf0.u[j] = f2b(fmaxf(v0, 0.0f));
            phf1.u[j] = f2b(fmaxf(v1, 0.0f));
        }
    }
    const float qt0 = qt[(size_t)bh * 32 + l16];
    const float qt1 = qt[(size_t)bh * 32 + 16 + l16];
    __syncthreads();

    const int aoff0 = (rb + l16) * KST;
    const int aoff1 = (rb + 16 + l16) * KST;
    const unsigned short* wsv = ws16 + WVOFF;
    const unsigned short* wst = ws16 + WTOFF;
    const unsigned short* ws2 = ws16 + SW2OFF;

    unsigned char vm[2][4];
    #pragma unroll
    for (int mt = 0; mt < 2; ++mt)
        #pragma unroll
        for (int r = 0; r < 4; ++r) vm[mt][r] = visb[rb + mt * 16 + quad * 4 + r];

    f32x4 hacc[2][2];
    #pragma unroll
    for (int mt = 0; mt < 2; ++mt)
        #pragma unroll
        for (int jt = 0; jt < 2; ++jt) hacc[mt][jt] = (f32x4){0.f, 0.f, 0.f, 0.f};
    #pragma unroll
    for (int kt = 0; kt < 8; ++kt) {
        s16x8 A0 = *(const s16x8*)&keyb[aoff0 + kt * 32 + quad * 8];
        s16x8 A1 = *(const s16x8*)&keyb[aoff1 + kt * 32 + quad * 8];
        #pragma unroll
        for (int jt = 0; jt < 2; ++jt) {
            s16x8 B = *(const s16x8*)(wst + (size_t)(jt * 9 + kt) * 512 + lane * 8);
            hacc[0][jt] = __builtin_amdgcn_mfma_f32_16x16x32_bf16(A0, B, hacc[0][jt], 0, 0, 0);
            hacc[1][jt] = __builtin_amdgcn_mfma_f32_16x16x32_bf16(A1, B, hacc[1][jt], 0, 0, 0);
        }
    }
    #pragma unroll
    for (int jt = 0; jt < 2; ++jt) {
        s16x8 B = *(const s16x8*)(wst + (size_t)(jt * 9 + 8) * 512 + lane * 8);
        hacc[0][jt] = __builtin_amdgcn_mfma_f32_16x16x32_bf16(phf0.v, B, hacc[0][jt], 0, 0, 0);
        hacc[1][jt] = __builtin_amdgcn_mfma_f32_16x16x32_bf16(phf1.v, B, hacc[1][jt], 0, 0, 0);
    }
    #pragma unroll
    for (int mt = 0; mt < 2; ++mt)
        #pragma unroll
        for (int jt = 0; jt < 2; ++jt) {
            float qv = jt ? qt1 : qt0;
            int rw = (mt * 16 + quad * 4) * SST + jt * 16 + l16;
            strip[rw]           = f2b(fmaxf(hacc[mt][jt][0] + qv, 0.0f));
            strip[rw + SST]     = f2b(fmaxf(hacc[mt][jt][1] + qv, 0.0f));
            strip[rw + 2 * SST] = f2b(fmaxf(hacc[mt][jt][2] + qv, 0.0f));
            strip[rw + 3 * SST] = f2b(fmaxf(hacc[mt][jt][3] + qv, 0.0f));
        }

    s16x8 H0 = *(const s16x8*)&strip[l16 * SST + quad * 8];
    s16x8 H1 = *(const s16x8*)&strip[(16 + l16) * SST + quad * 8];
    float mloc[16];
    #pragma unroll
    for (int ct = 0; ct < 16; ++ct) {
        f32x4 a0 = (f32x4){0.f, 0.f, 0.f, 0.f};
        f32x4 a1 = (f32x4){0.f, 0.f, 0.f, 0.f};
        s16x8 B = *(const s16x8*)(ws2 + ((size_t)ct * 64 + lane) * 8);
        a0 = __builtin_amdgcn_mfma_f32_16x16x32_bf16(H0, B, a0, 0, 0, 0);
        a1 = __builtin_amdgcn_mfma_f32_16x16x32_bf16(H1, B, a1, 0, 0, 0);
        float sb2c = sb2[ct * 16 + l16];
        float ml = -3.0e38f;
        #pragma unroll
        for (int r = 0; r < 4; ++r) {
            float s0 = vm[0][r] ? (a0[r] + sb2c) : -1e9f;
            float s1 = vm[1][r] ? (a1[r] + sb2c) : -1e9f;
            ml = fmaxf(ml, fmaxf(s0, s1));
        }
        ml = fmaxf(ml, __shfl_xor(ml, 16));
        ml = fmaxf(ml, __shfl_xor(ml, 32));
        mloc[ct] = ml;
    }
    __syncthreads();
    #pragma unroll 1
    for (int w = 0; w < 4; ++w) {
        if (wvid == w && lane < 16) {
            #pragma unroll
            for (int ct = 0; ct < 16; ++ct) {
                int x = ct * 16 + lane;
                poolA[x] = (w == 0) ? mloc[ct] : fmaxf(poolA[x], mloc[ct]);
            }
        }
        __syncthreads();
    }
    float Mf[16];
    #pragma unroll
    for (int ct = 0; ct < 16; ++ct) Mf[ct] = poolA[ct * 16 + l16];

    float lsp[16], aggp[16];
    #pragma unroll
    for (int ct = 0; ct < 16; ++ct) { lsp[ct] = 0.0f; aggp[ct] = 0.0f; }

    #pragma unroll 1
    for (int ck = 0; ck < 8; ++ck) {
        float ev[2][2][4];
        #pragma unroll
        for (int ctl = 0; ctl < 2; ++ctl) {
            int ct = ck * 2 + ctl;
            f32x4 a0 = (f32x4){0.f, 0.f, 0.f, 0.f};
            f32x4 a1 = (f32x4){0.f, 0.f, 0.f, 0.f};
            s16x8 B = *(const s16x8*)(ws2 + ((size_t)ct * 64 + lane) * 8);
            a0 = __builtin_amdgcn_mfma_f32_16x16x32_bf16(H0, B, a0, 0, 0, 0);
            a1 = __builtin_amdgcn_mfma_f32_16x16x32_bf16(H1, B, a1, 0, 0, 0);
            float sb2c = sb2[ct * 16 + l16];
            float M = Mf[ct];
            float ls = 0.0f;
            #pragma unroll
            for (int r = 0; r < 4; ++r) {
                float s0 = vm[0][r] ? (a0[r] + sb2c) : -1e9f;
                float s1 = vm[1][r] ? (a1[r] + sb2c) : -1e9f;
                float e0 = __expf(s0 - M);
                float e1 = __expf(s1 - M);
                ev[ctl][0][r] = e0;
                ev[ctl][1][r] = e1;
                ls += e0 + e1;
            }
            lsp[ct] = ls;
        }
        f32x4 acc[2][2];
        #pragma unroll
        for (int mt = 0; mt < 2; ++mt)
            #pragma unroll
            for (int ctl = 0; ctl < 2; ++ctl) acc[mt][ctl] = (f32x4){0.f, 0.f, 0.f, 0.f};
        #pragma unroll
        for (int kt = 0; kt < 8; ++kt) {
            s16x8 A0 = *(const s16x8*)&keyb[aoff0 + kt * 32 + quad * 8];
            s16x8 A1 = *(const s16x8*)&keyb[aoff1 + kt * 32 + quad * 8];
            #pragma unroll
            for (int ctl = 0; ctl < 2; ++ctl) {
                s16x8 B = *(const s16x8*)(wsv + ((size_t)((ck * 2 + ctl) * 9 + kt) * 512) + lane * 8);
                acc[0][ctl] = __builtin_amdgcn_mfma_f32_16x16x32_bf16(A0, B, acc[0][ctl], 0, 0, 0);
                acc[1][ctl] = __builtin_amdgcn_mfma_f32_16x16x32_bf16(A1, B, acc[1][ctl], 0, 0, 0);
            }
        }
        #pragma unroll
        for (int ctl = 0; ctl < 2; ++ctl) {
            s16x8 B = *(const s16x8*)(wsv + ((size_t)((ck * 2 + ctl) * 9 + 8) * 512) + lane * 8);
            acc[0][ctl] = __builtin_amdgcn_mfma_f32_16x16x32_bf16(phf0.v, B, acc[0][ctl], 0, 0, 0);
            acc[1][ctl] = __builtin_amdgcn_mfma_f32_16x16x32_bf16(phf1.v, B, acc[1][ctl], 0, 0, 0);
        }
        #pragma unroll
        for (int ctl = 0; ctl < 2; ++ctl) {
            const int ct = ck * 2 + ctl;
            float pb = poolB[ct * 16 + l16];
            float a = aggp[ct];
            #pragma unroll
            for (int mt = 0; mt < 2; ++mt)
                #pragma unroll
                for (int r = 0; r < 4; ++r)
                    a = fmaf(ev[ctl][mt][r], acc[mt][ctl][r] + pb, a);
            aggp[ct] = a;
        }
    }

    __syncthreads();
    #pragma unroll
    for (int ct = 0; ct < 16; ++ct) {
        float a = aggp[ct];
        a += __shfl_xor(a, 16);
        a += __shfl_xor(a, 32);
        float l = lsp[ct];
        l += __shfl_xor(l, 16);
        l += __shfl_xor(l, 32);
        if (lane < 16) {
            aggpool[wvid * 256 + ct * 16 + lane] = a;
            lpool[wvid * 256 + ct * 16 + lane] = l;
        }
    }
    __syncthreads();
    {
        float asum = aggpool[t] + aggpool[256 + t] + aggpool[512 + t] + aggpool[768 + t];
        float lsum = lpool[t] + lpool[256 + t] + lpool[512 + t] + lpool[768 + t];
        aggout[(size_t)bh * CC + t] = asum / lsum;
    }
}

// ---------------- ffo2: Wo + LN2 + FF, 2 rows/block, packed uint weight loads ----------------
__global__ __launch_bounds__(256, 4)
void cft_ffo2(const float* __restrict__ aggp, const float* __restrict__ qin,
              const float* __restrict__ bo,
              const float* __restrict__ ln2g, const float* __restrict__ ln2b,
              const unsigned short* __restrict__ ws16,
              const float* __restrict__ fb1, const float* __restrict__ fb2,
              float* __restrict__ out)
{
    __shared__ __align__(16) float aggL[2][CC];
    __shared__ __align__(16) float xlnL[2][CC];
    __shared__ __align__(16) float ffh[2][HIDN];
    __shared__ __align__(16) float part[2][2][CC];   // [half][row][c]
    __shared__ float red[4];
    const int t = threadIdx.x;
    const int b0 = blockIdx.x * 2;
    const unsigned short* wob  = ws16 + WOB_OFF;
    const unsigned short* fw1b = ws16 + FW1B_OFF;
    const unsigned short* fw2b = ws16 + FW2B_OFF;

    float xq[2];
    #pragma unroll
    for (int i = 0; i < 2; ++i) {
        aggL[i][t] = aggp[(size_t)(b0 + i) * CC + t];
        xq[i] = qin[(size_t)(b0 + i) * CC + t];
    }
    __syncthreads();

    // Wo matvec (c = t)
    float ao[2];
    { float b = bo[t]; ao[0] = b; ao[1] = b; }
    for (int k4 = 0; k4 < CC / 4; ++k4) {
        float4 a0 = *(const float4*)&aggL[0][k4 * 4];
        float4 a1 = *(const float4*)&aggL[1][k4 * 4];
        const unsigned short* w = wob + (size_t)(k4 * 4) * CC + t;
        float w0 = b2f(w[0]), w1 = b2f(w[CC]), w2 = b2f(w[2 * CC]), w3 = b2f(w[3 * CC]);
        ao[0] = fmaf(a0.x, w0, fmaf(a0.y, w1, fmaf(a0.z, w2, fmaf(a0.w, w3, ao[0]))));
        ao[1] = fmaf(a1.x, w0, fmaf(a1.y, w1, fmaf(a1.z, w2, fmaf(a1.w, w3, ao[1]))));
    }
    float xrs[2] = { ao[0] + xq[0], ao[1] + xq[1] };

    // LN2
    #pragma unroll
    for (int row = 0; row < 2; ++row) {
        float x = xrs[row];
        float mean = block_sum_256(x, red) * (1.0f / CC);
        float d = x - mean;
        float var = block_sum_256(d * d, red) * (1.0f / CC);
        xlnL[row][t] = d * rsqrtf(var + EPSL) * ln2g[t] + ln2b[t];
    }
    __syncthreads();

    // ff1: h = {2t, 2t+1, 2t+512, 2t+513}; packed uint loads (4B/lane)
    {
        const int h0 = 2 * t;
        float acc[2][4];
        acc[0][0] = acc[1][0] = fb1[h0];
        acc[0][1] = acc[1][1] = fb1[h0 + 1];
        acc[0][2] = acc[1][2] = fb1[h0 + 512];
        acc[0][3] = acc[1][3] = fb1[h0 + 513];
        for (int k4 = 0; k4 < CC / 4; ++k4) {
            float4 x0 = *(const float4*)&xlnL[0][k4 * 4];
            float4 x1 = *(const float4*)&xlnL[1][k4 * 4];
            float xa0[4] = {x0.x, x0.y, x0.z, x0.w};
            float xa1[4] = {x1.x, x1.y, x1.z, x1.w};
            #pragma unroll
            for (int kk = 0; kk < 4; ++kk) {
                const int k = k4 * 4 + kk;
                unsigned wA = *(const unsigned*)&fw1b[(size_t)k * HIDN + h0];
                unsigned wB = *(const unsigned*)&fw1b[(size_t)k * HIDN + h0 + 512];
                float wl = blo(wA), wh = bhi(wA), wl2 = blo(wB), wh2 = bhi(wB);
                acc[0][0] = fmaf(xa0[kk], wl, acc[0][0]);
                acc[0][1] = fmaf(xa0[kk], wh, acc[0][1]);
                acc[0][2] = fmaf(xa0[kk], wl2, acc[0][2]);
                acc[0][3] = fmaf(xa0[kk], wh2, acc[0][3]);
                acc[1][0] = fmaf(xa1[kk], wl, acc[1][0]);
                acc[1][1] = fmaf(xa1[kk], wh, acc[1][1]);
                acc[1][2] = fmaf(xa1[kk], wl2, acc[1][2]);
                acc[1][3] = fmaf(xa1[kk], wh2, acc[1][3]);
            }
        }
        #pragma unroll
        for (int row = 0; row < 2; ++row) {
            ffh[row][h0]       = fmaxf(acc[row][0], 0.0f);
            ffh[row][h0 + 1]   = fmaxf(acc[row][1], 0.0f);
            ffh[row][h0 + 512] = fmaxf(acc[row][2], 0.0f);
            ffh[row][h0 + 513] = fmaxf(acc[row][3], 0.0f);
        }
    }
    __syncthreads();

    // ff2: half the threads per h-half, c-pairs; packed uint loads
    {
        const int u = t & 127;
        const int half = t >> 7;
        const int c0 = 2 * u;
        const int hbase = half * 512;
        float oacc[2][2] = {{0.f, 0.f}, {0.f, 0.f}};   // [row][c-slot]
        for (int h4 = 0; h4 < 128; ++h4) {
            const int h = hbase + h4 * 4;
            #pragma unroll
            for (int hh = 0; hh < 4; ++hh) {
                unsigned w = *(const unsigned*)&fw2b[(size_t)(h + hh) * CC + c0];
                float w0 = blo(w), w1 = bhi(w);
                float hv0 = ffh[0][h + hh];
                float hv1 = ffh[1][h + hh];
                oacc[0][0] = fmaf(hv0, w0, oacc[0][0]);
                oacc[0][1] = fmaf(hv0, w1, oacc[0][1]);
                oacc[1][0] = fmaf(hv1, w0, oacc[1][0]);
                oacc[1][1] = fmaf(hv1, w1, oacc[1][1]);
            }
        }
        part[half][0][c0]     = oacc[0][0];
        part[half][0][c0 + 1] = oacc[0][1];
        part[half][1][c0]     = oacc[1][0];
        part[half][1][c0 + 1] = oacc[1][1];
    }
    __syncthreads();
    #pragma unroll
    for (int row = 0; row < 2; ++row)
        out[(size_t)(b0 + row) * CC + t] =
            xrs[row] + fb2[t] + part[0][row][t] + part[1][row][t];
}

extern "C" void kernel_launch(void* const* d_in, const int* in_sizes, int n_in,
                              void* d_out, int out_size, void* d_ws, size_t ws_size,
                              hipStream_t stream) {
    const float* qin  = (const float*)d_in[0];
    const float* kin  = (const float*)d_in[1];
    const float* rel  = (const float*)d_in[2];
    const int*   vis  = (const int*)  d_in[3];
    const float* ln1g = (const float*)d_in[4];
    const float* ln1b = (const float*)d_in[5];
    const float* ln2g = (const float*)d_in[6];
    const float* ln2b = (const float*)d_in[7];
    const float* Wq   = (const float*)d_in[8];
    const float* Wk   = (const float*)d_in[9];
    const float* Wv   = (const float*)d_in[10];
    const float* pw1  = (const float*)d_in[11];
    const float* pb1  = (const float*)d_in[12];
    const float* pw2  = (const float*)d_in[13];
    const float* pb2  = (const float*)d_in[14];
    const float* sw1  = (const float*)d_in[15];
    const float* sb1  = (const float*)d_in[16];
    const float* sw2  = (const float*)d_in[17];
    const float* sb2  = (const float*)d_in[18];
    const float* Wo   = (const float*)d_in[19];
    const float* bo   = (const float*)d_in[20];
    const float* fw1  = (const float*)d_in[21];
    const float* fb1  = (const float*)d_in[22];
    const float* fw2  = (const float*)d_in[23];
    const float* fb2  = (const float*)d_in[24];
    (void)in_sizes; (void)n_in; (void)out_size; (void)ws_size;

    unsigned short* ws16 = (unsigned short*)d_ws;
    float* qt   = (float*)((char*)d_ws + QT_BYTE_OFF);
    float* aggb = (float*)((char*)d_ws + AGG_BYTE_OFF);
    float* wqt  = (float*)((char*)d_ws + WQT_BYTE_OFF);
    float* qtc  = (float*)((char*)d_ws + QTC_BYTE_OFF);
    float* o = (float*)d_out;

    prep_all<<<dim3(397), dim3(256), 0, stream>>>(
        Wk, Wv, Wq, pw2, sw1, sw2, fw1, fw2, Wo, pb2, sb1, ws16, wqt, qtc);
    qprep2<<<dim3(256), dim3(256), 0, stream>>>(qin, ln1g, ln1b, wqt, qtc, qt);
    cft_attn<<<dim3(1024), dim3(256), 0, stream>>>(
        kin, rel, vis, pw1, pb1, pb2, sb2, ws16, qt, aggb);
    cft_ffo2<<<dim3(512), dim3(256), 0, stream>>>(
        aggb, qin, bo, ln2g, ln2b, ws16, fb1, fb2, o);
}